// Round 4
// baseline (1726.657 us; speedup 1.0000x reference)
//
#include <hip/hip_runtime.h>
#include <math.h>

#define N_ANCH 76725
#define SORT_N 4096
#define NBKT 1024
#define BBASE 0x3D40u

typedef _Float16 f16;
typedef _Float16 f16x8 __attribute__((ext_vector_type(8)));
typedef float f32x4 __attribute__((ext_vector_type(4)));

__device__ __forceinline__ int pick5(int l, int a, int b, int c, int d, int e) {
  int r = a;
  if (l == 1) r = b;
  if (l == 2) r = c;
  if (l == 3) r = d;
  if (l == 4) r = e;
  return r;
}

// 64-position tiling (8x8): 139 tiles (conv_out2)
__device__ __forceinline__ void tile_to_level(int tile, int& lvl, int& t) {
  int l = 0;
  if (tile >= 100) l = 1;
  if (tile >= 125) l = 2;
  if (tile >= 134) l = 3;
  if (tile >= 138) l = 4;
  lvl = l;
  t = tile - pick5(l, 0, 100, 125, 134, 138);
}

// 64-linear-position tiling: 135 tiles (featcvt / epi)
__device__ __forceinline__ int tile64_lvl(int bx, int& t) {
  int l = 0;
  if (bx >= 100) l = 1;
  if (bx >= 125) l = 2;
  if (bx >= 132) l = 3;
  if (bx >= 134) l = 4;
  t = bx - pick5(l, 0, 100, 125, 132, 134);
  return l;
}

// fp32 -> f16 hi + (scaled by 2^12) f16 lo.  hi forced away from f16-denormal range.
__device__ __forceinline__ void split16(float v, f16& h, f16& l) {
  f16 hh = (f16)v;
  if (fabsf(v) < 6.103515625e-5f) hh = (f16)0.f;
  h = hh;
  l = (f16)((v - (float)hh) * 4096.f);
}

// async global->LDS, 16B per lane; dst wave-uniform base, lane i lands at dst+16*i
__device__ __forceinline__ void glds16h(const void* g, void* l) {
  __builtin_amdgcn_global_load_lds(
      (const __attribute__((address_space(1))) unsigned int*)g,
      (__attribute__((address_space(3))) unsigned int*)l, 16, 0, 0);
}

__device__ __forceinline__ void glds16(const float* g, float* l) {
  __builtin_amdgcn_global_load_lds(
      (const __attribute__((address_space(1))) unsigned int*)g,
      (__attribute__((address_space(3))) unsigned int*)l, 16, 0, 0);
}

// ---------------- feats fp32 NCHW -> packed [pos][ci] hi/lo f16 planes (reg path) ----------------
struct FcvArgs {
  const float* f[5];
  f16* hi;
  f16* lo;
  unsigned short* zbuf;
};

__global__ __launch_bounds__(256) void featcvt_k(FcvArgs a) {
  __shared__ float tile[32][65];
  int t;
  const int l = tile64_lvl(blockIdx.x, t);
  const int W = 80 >> l, HW = W * W;
  const int p0 = t * 64;
  const int apos = pick5(l, 0, 6400, 8000, 8400, 8500);
  const int ci0 = blockIdx.y * 32;
  const int tid = threadIdx.x;
  if (blockIdx.x == 0 && blockIdx.y == 0 && tid < 32) a.zbuf[tid] = 0;
  const float* __restrict__ src = a.f[l];
  #pragma unroll
  for (int i = 0; i < 8; i++) {
    const int j = tid + 256 * i;
    const int ci = j >> 6, p = j & 63;
    float v = 0.f;
    if (p0 + p < HW) v = src[(ci0 + ci) * HW + p0 + p];
    tile[ci][p] = v;
  }
  __syncthreads();
  const int p_l = tid >> 2, cq = tid & 3;
  if (p0 + p_l < HW) {
    union { f16 h[8]; uint4 v; } uh, ul;
    #pragma unroll
    for (int u = 0; u < 8; u++) split16(tile[cq * 8 + u][p_l], uh.h[u], ul.h[u]);
    const size_t base = (size_t)(apos + p0 + p_l) * 256 + ci0 + cq * 8;
    *(uint4*)(a.hi + base) = uh.v;
    *(uint4*)(a.lo + base) = ul.v;
  }
}

// ---------------- reg trunk weights -> hi/lo f16, layout [c=tap*8+ciq][co 256][k 32] ----------------
__global__ __launch_bounds__(256) void wsplit_k(const float* __restrict__ src,
                                                f16* __restrict__ whi,
                                                f16* __restrict__ wlo) {
  const int e = blockIdx.x * 256 + threadIdx.x;  // 0..589823
  const int k = e & 31, co = (e >> 5) & 255, c = e >> 13;
  const int tap = c >> 3, ciq = c & 7;
  const int ci = ciq * 32 + k;
  const float v = src[((size_t)co * 256 + ci) * 9 + tap];
  f16 h, lo;
  split16(v, h, lo);
  whi[e] = h;
  wlo[e] = lo;
}

// ---------------- MFMA reg trunk: fp16x2-split implicit GEMM, 128co x 128pos, K-split-2 ----------------
struct TrkArgs {
  const f16* in_hi;
  const f16* in_lo;
  const f16* w_hi;
  const f16* w_lo;
  float* acc;
  const f16* zbuf;
};

__global__ __launch_bounds__(256, 2) void trunk_mm(TrkArgs a) {
  __shared__ __align__(16) f16 Xh[2][4096];
  __shared__ __align__(16) f16 Xl[2][4096];
  __shared__ __align__(16) f16 Wh[2][4096];
  __shared__ __align__(16) f16 Wl[2][4096];
  const int bx = blockIdx.x;             // 0..295; combo=bx&3 = (cog,kh)
  const int combo = bx & 3, tl = bx >> 2;
  const int cog = combo >> 1, kh = combo & 1;
  int l = 0;
  if (tl >= 50) l = 1;
  if (tl >= 65) l = 2;
  if (tl >= 71) l = 3;
  if (tl >= 73) l = 4;
  const int t = tl - pick5(l, 0, 50, 65, 71, 73);
  const int W = 80 >> l, HW = W * W, tX = (W + 7) >> 3;
  const int ty0 = (t / tX) * 16, tx0 = (t % tX) * 8;
  const int apos = pick5(l, 0, 6400, 8000, 8400, 8500);
  const int co0 = cog * 128;
  const int tid = threadIdx.x, lane = tid & 63, wv = tid >> 6;
  const int ln15 = lane & 15, lh = lane >> 4;
  const int wco = wv & 1, wpos = wv >> 1;
  const f16* __restrict__ ihi = a.in_hi;
  const f16* __restrict__ ilo = a.in_lo;
  const f16* __restrict__ whi = a.w_hi;
  const f16* __restrict__ wlo = a.w_lo;

  f32x4 accA[4][4] = {};
  f32x4 accB[4][4] = {};

  auto stage = [&](int c, int buf) {
    const int tap = c >> 3, ciq = c & 7;
    const int dy = tap / 3 - 1, dx = tap - (tap / 3) * 3 - 1;
    // X: [pos 128][slot 4], swizzle baked into per-lane source (k-slot = kq ^ (pos&3))
    #pragma unroll
    for (int i = 0; i < 2; i++) {
      const int s = (wv * 2 + i) * 64 + lane;
      const int pos = s >> 2, kq = s & 3;
      const int kqd = kq ^ (pos & 3);
      const int gy = ty0 + (pos >> 3) + dy, gx = tx0 + (pos & 7) + dx;
      const bool v = (unsigned)gy < (unsigned)W && (unsigned)gx < (unsigned)W;
      const int off = (apos + gy * W + gx) * 256 + ciq * 32 + kqd * 8;
      glds16h(v ? (const void*)(ihi + off) : (const void*)a.zbuf, &Xh[buf][(wv * 2 + i) * 512]);
      glds16h(v ? (const void*)(ilo + off) : (const void*)a.zbuf, &Xl[buf][(wv * 2 + i) * 512]);
    }
    // W: [co 128][slot 4], same source-side swizzle
    const f16* wh = whi + (size_t)c * 8192;
    const f16* wl = wlo + (size_t)c * 8192;
    #pragma unroll
    for (int i = 0; i < 2; i++) {
      const int s = (wv * 2 + i) * 64 + lane;
      const int col = s >> 2, kq = s & 3;
      const int kqd = kq ^ (col & 3);
      const int off = (co0 + col) * 32 + kqd * 8;
      glds16h(wh + off, &Wh[buf][(wv * 2 + i) * 512]);
      glds16h(wl + off, &Wl[buf][(wv * 2 + i) * 512]);
    }
  };

  const int c0 = kh * 36;
  stage(c0, 0);
  __syncthreads();
  for (int j = 0; j < 36; j++) {
    const int b = j & 1;
    if (j < 35) stage(c0 + j + 1, b ^ 1);
    const int slot = (lh ^ (ln15 & 3)) * 8;
    const int aro = (wco * 64 + ln15) * 32 + slot;
    const int bro = (wpos * 64 + ln15) * 32 + slot;
    f16x8 ah[4], al[4];
    #pragma unroll
    for (int mi = 0; mi < 4; mi++) {
      ah[mi] = *(const f16x8*)&Wh[b][aro + mi * 512];
      al[mi] = *(const f16x8*)&Wl[b][aro + mi * 512];
    }
    #pragma unroll
    for (int ni = 0; ni < 4; ni++) {
      const f16x8 bhv = *(const f16x8*)&Xh[b][bro + ni * 512];
      const f16x8 blv = *(const f16x8*)&Xl[b][bro + ni * 512];
      #pragma unroll
      for (int mi = 0; mi < 4; mi++) {
        accA[mi][ni] = __builtin_amdgcn_mfma_f32_16x16x32_f16(ah[mi], bhv, accA[mi][ni], 0, 0, 0);
        accB[mi][ni] = __builtin_amdgcn_mfma_f32_16x16x32_f16(ah[mi], blv, accB[mi][ni], 0, 0, 0);
        accB[mi][ni] = __builtin_amdgcn_mfma_f32_16x16x32_f16(al[mi], bhv, accB[mi][ni], 0, 0, 0);
      }
    }
    __syncthreads();
  }

  // epilogue: combine hi-acc + 2^-12 * cross-acc, atomically accumulate (exactly 2 addends/elem)
  const int aoffF = pick5(l, 0, 1638400, 2048000, 2150400, 2176000);
  float* __restrict__ dst = a.acc + aoffF;
  #pragma unroll
  for (int ni = 0; ni < 4; ni++) {
    const int pos = wpos * 64 + ni * 16 + ln15;
    const int gy = ty0 + (pos >> 3), gx = tx0 + (pos & 7);
    if (gy < W && gx < W) {
      #pragma unroll
      for (int mi = 0; mi < 4; mi++) {
        const int co = co0 + wco * 64 + mi * 16 + lh * 4;
        float* d = dst + (size_t)co * HW + gy * W + gx;
        #pragma unroll
        for (int r = 0; r < 4; r++)
          atomicAdd(d + (size_t)r * HW, accA[mi][ni][r] + accB[mi][ni][r] * 2.44140625e-4f);
      }
    }
  }
}

// ---------------- reg per-layer epilogue: bias+relu, re-split (or fp32 in-place for last) ----------------
struct EpiArgs {
  float* acc;
  const float* bias;
  f16* hi;
  f16* lo;
  int last;
};

__global__ __launch_bounds__(256) void epi_k(EpiArgs a) {
  __shared__ float tile[32][65];
  int t;
  const int l = tile64_lvl(blockIdx.x, t);
  const int W = 80 >> l, HW = W * W;
  const int p0 = t * 64;
  const int apos = pick5(l, 0, 6400, 8000, 8400, 8500);
  const int ci0 = blockIdx.y * 32;
  const int tid = threadIdx.x;
  float* __restrict__ src = a.acc + (size_t)apos * 256;
  const float* __restrict__ bias = a.bias;
  #pragma unroll
  for (int i = 0; i < 8; i++) {
    const int j = tid + 256 * i;
    const int ci = j >> 6, p = j & 63;
    float v = 0.f;
    if (p0 + p < HW) v = src[(size_t)(ci0 + ci) * HW + p0 + p];
    tile[ci][p] = fmaxf(v + bias[ci0 + ci], 0.f);
  }
  __syncthreads();
  if (a.last) {
    #pragma unroll
    for (int i = 0; i < 8; i++) {
      const int j = tid + 256 * i;
      const int ci = j >> 6, p = j & 63;
      if (p0 + p < HW) src[(size_t)(ci0 + ci) * HW + p0 + p] = tile[ci][p];
    }
  } else {
    const int p_l = tid >> 2, cq = tid & 3;
    if (p0 + p_l < HW) {
      union { f16 h[8]; uint4 v; } uh, ul;
      #pragma unroll
      for (int u = 0; u < 8; u++) split16(tile[cq * 8 + u][p_l], uh.h[u], ul.h[u]);
      const size_t base = (size_t)(apos + p0 + p_l) * 256 + ci0 + cq * 8;
      *(uint4*)(a.hi + base) = uh.v;
      *(uint4*)(a.lo + base) = ul.v;
    }
  }
}

// ---------------- baseline fp32 path (cls head): weight re-layout ----------------
struct TrunkArgs {
  const float* in[2][5];
  float* out[2][5];
  const float* w[2];   // re-laid weights: w[head] + cog*2304*64 + (ci*9+tap)*64 + co_in_64
  const float* b[2];
};

struct WtrArgs {
  const float* src[2];  // original w[co][ci][tap] per head, one layer
  float* dst;           // wt2: [head][cog][2304][64]
};

__global__ __launch_bounds__(256) void wtr_k(WtrArgs a) {
  __shared__ float tile[72][65];
  const int r0 = blockIdx.x * 72;   // 32 groups
  const int cog = blockIdx.y;       // 4 groups of 64 co
  const int co0 = cog * 64;
  const int head = blockIdx.z;
  const float* __restrict__ src = a.src[head];
  float* __restrict__ dst = a.dst + ((size_t)(head * 4 + cog) * 2304 + r0) * 64;
  const int tid = threadIdx.x;
  #pragma unroll
  for (int i = 0; i < 18; i++) {
    int e = tid + 256 * i;  // < 4608
    int co = e / 72;
    int r = e - co * 72;
    tile[r][co] = src[(size_t)(co0 + co) * 2304 + r0 + r];
  }
  __syncthreads();
  #pragma unroll
  for (int i = 0; i < 18; i++) {
    int e = tid + 256 * i;
    int r = e >> 6;
    int co = e & 63;
    dst[(size_t)r * 64 + co] = tile[r][co];
  }
}

// ---------------- baseline fp32 trunk conv (cls head, bit-exact vs passing baseline) ----------------
__device__ __forceinline__ void a_load(const float* __restrict__ in, int ci0,
                                       int ty0, int tx0, int W, int HW, int tid,
                                       float a_reg[6]) {
  const float* inc = in + ci0 * HW;
  #pragma unroll
  for (int i = 0; i < 6; i++) {
    int e = tid + 256 * i;
    float v = 0.f;
    if (e < 1440) {
      int ci = e / 180;
      int rem = e - ci * 180;
      int yy = rem / 10;
      int xx = rem - yy * 10;
      int gy = ty0 + yy - 1, gx = tx0 + xx - 1;
      if ((unsigned)gy < (unsigned)W && (unsigned)gx < (unsigned)W)
        v = inc[ci * HW + gy * W + gx];
    }
    a_reg[i] = v;
  }
}

__device__ __forceinline__ void a_store(int tid, const float a_reg[6],
                                        float As[8][18][12]) {
  #pragma unroll
  for (int i = 0; i < 6; i++) {
    int e = tid + 256 * i;
    if (e < 1440) {
      int ci = e / 180;
      int rem = e - ci * 180;
      int yy = rem / 10;
      int xx = rem - yy * 10;
      As[ci][yy][xx] = a_reg[i];
    }
  }
}

__device__ __forceinline__ void stage_w(const float* __restrict__ wchunk,
                                        float* wbuf, int wv, int lane) {
  #pragma unroll
  for (int i = 0; i < 5; i++) {
    int j = wv + 4 * i;           // wave-uniform
    if (j < 18) glds16(wchunk + j * 256 + lane * 4, wbuf + j * 256);
  }
}

__global__ __launch_bounds__(256) void conv_trunk(TrunkArgs args) {
  __shared__ float As[2][8][18][12];   // 2 x 6.75 KB
  __shared__ float Ws[2][72][64];      // 2 x 18 KB
  int l = 0;
  if (blockIdx.x >= 50) l = 1;
  if (blockIdx.x >= 65) l = 2;
  if (blockIdx.x >= 71) l = 3;
  if (blockIdx.x >= 73) l = 4;
  const int lvl = l;
  const int t = blockIdx.x - pick5(l, 0, 50, 65, 71, 73);
  const int W = 80 >> lvl;
  const int HW = W * W;
  const int tX = (W + 7) >> 3;
  const int ty0 = (t / tX) * 16, tx0 = (t % tX) * 8;
  const int head = blockIdx.z;
  const int co0 = blockIdx.y << 6;
  const float* __restrict__ in = args.in[head][lvl];
  float* __restrict__ out = args.out[head][lvl];
  const float* __restrict__ wsrc = args.w[head] + (size_t)blockIdx.y * 2304 * 64;
  const int tid = threadIdx.x;
  const int lane = tid & 63, wv = tid >> 6;
  const int cop = tid & 15;
  const int ry = tid >> 4;
  const int co_sub = cop << 2;
  float acc[8][4] = {};
  float a_reg[6];

  stage_w(wsrc, &Ws[0][0][0], wv, lane);
  a_load(in, 0, ty0, tx0, W, HW, tid, a_reg);
  a_store(tid, a_reg, As[0]);
  __syncthreads();

  for (int k = 0; k < 32; k++) {
    const int kb = k & 1;
    const bool more = k < 31;
    if (more) {
      stage_w(wsrc + (size_t)(k + 1) * 4608, &Ws[kb ^ 1][0][0], wv, lane);
      a_load(in, (k + 1) * 8, ty0, tx0, W, HW, tid, a_reg);
    }
    #pragma unroll 2
    for (int ci = 0; ci < 8; ci++) {
      #pragma unroll
      for (int ty = 0; ty < 3; ty++) {
        const float* ar = &As[kb][ci][ry + ty][0];
        float4 a0 = *(const float4*)ar;
        float4 a1 = *(const float4*)(ar + 4);
        float2 a2 = *(const float2*)(ar + 8);
        float a[10] = {a0.x, a0.y, a0.z, a0.w, a1.x, a1.y, a1.z, a1.w, a2.x, a2.y};
        #pragma unroll
        for (int tx = 0; tx < 3; tx++) {
          const float* wr = &Ws[kb][ci * 9 + ty * 3 + tx][co_sub];
          float4 wvv = *(const float4*)wr;
          #pragma unroll
          for (int p = 0; p < 8; p++) {
            acc[p][0] = fmaf(a[tx + p], wvv.x, acc[p][0]);
            acc[p][1] = fmaf(a[tx + p], wvv.y, acc[p][1]);
            acc[p][2] = fmaf(a[tx + p], wvv.z, acc[p][2]);
            acc[p][3] = fmaf(a[tx + p], wvv.w, acc[p][3]);
          }
        }
      }
    }
    if (more) {
      a_store(tid, a_reg, As[kb ^ 1]);
      __syncthreads();
    }
  }
  const float4 bias = *(const float4*)&args.b[head][co0 + co_sub];
  const int oy = ty0 + ry;
  if (oy < W) {
    #pragma unroll
    for (int p = 0; p < 8; p++) {
      int ox = tx0 + p;
      if (ox < W) {
        int base = oy * W + ox;
        out[(co0 + co_sub + 0) * HW + base] = fmaxf(acc[p][0] + bias.x, 0.f);
        out[(co0 + co_sub + 1) * HW + base] = fmaxf(acc[p][1] + bias.y, 0.f);
        out[(co0 + co_sub + 2) * HW + base] = fmaxf(acc[p][2] + bias.z, 0.f);
        out[(co0 + co_sub + 3) * HW + base] = fmaxf(acc[p][3] + bias.w, 0.f);
      }
    }
  }
}

// ---------------- output-conv weight transpose: -> wt2o[g][row=ci*9+tap][16] ----------------
struct Out2Args {
  const float* in[2][5];
  const float* w;
  const float* b[2];
  float* dst[2];
};

__global__ __launch_bounds__(256) void wtro_k(const float* __restrict__ cls_ow,
                                              const float* __restrict__ reg_ow,
                                              float* __restrict__ dst) {
  int r = blockIdx.x * 256 + threadIdx.x;   // 0..2303
  if (r >= 2304) return;
  for (int g = 0; g < 5; g++) {
    #pragma unroll
    for (int s = 0; s < 16; s++) {
      int w = s >> 2, c = s & 3;
      float v = 0.f;
      if (w < 3 && c < 3) {
        int cl = 3 * w + c;
        v = (g == 0) ? cls_ow[(size_t)cl * 2304 + r]
                     : reg_ow[(size_t)((g - 1) * 9 + cl) * 2304 + r];
      }
      dst[((size_t)g * 2304 + r) * 16 + s] = v;
    }
  }
}

// ---------------- fused output convs (unchanged) ----------------
__device__ __forceinline__ void ao_load(const float* __restrict__ in, int ci0,
                                        int ty0, int tx0, int W, int HW, int tid,
                                        float a_reg[5]) {
  const float* inc = in + ci0 * HW;
  #pragma unroll
  for (int i = 0; i < 5; i++) {
    int e = tid + 192 * i;
    float v = 0.f;
    if (e < 800) {
      int ci = e / 100;
      int rem = e - ci * 100;
      int yy = rem / 10;
      int xx = rem - yy * 10;
      int gy = ty0 + yy - 1, gx = tx0 + xx - 1;
      if ((unsigned)gy < (unsigned)W && (unsigned)gx < (unsigned)W)
        v = inc[ci * HW + gy * W + gx];
    }
    a_reg[i] = v;
  }
}

__device__ __forceinline__ void ao_store(int tid, const float a_reg[5],
                                         float As[8][10][12]) {
  #pragma unroll
  for (int i = 0; i < 5; i++) {
    int e = tid + 192 * i;
    if (e < 800) {
      int ci = e / 100;
      int rem = e - ci * 100;
      int yy = rem / 10;
      int xx = rem - yy * 10;
      As[ci][yy][xx] = a_reg[i];
    }
  }
}

__global__ __launch_bounds__(192) void conv_out2(Out2Args args) {
  __shared__ float As[2][8][10][12];
  __shared__ __align__(16) float Wg[2][8][9][16];
  int lvl, t;
  tile_to_level(blockIdx.x, lvl, t);
  const int g = blockIdx.y;
  const int head = (g == 0) ? 0 : 1;
  const int co0 = (g == 0) ? 0 : (g - 1) * 9;
  const int W = 80 >> lvl;
  const int HW = W * W;
  const int tX = (W + 7) >> 3;
  const int ty0 = (t / tX) * 8, tx0 = (t % tX) * 8;
  const float* __restrict__ in = args.in[head][lvl];
  const float* __restrict__ wg = args.w + (size_t)g * 2304 * 16;
  const int tid = threadIdx.x;
  const int wv = tid >> 6;
  const int lane = tid & 63;
  const int y = lane >> 3, x = lane & 7;
  float acc0 = 0.f, acc1 = 0.f, acc2 = 0.f;
  float a_reg[5];
  float4 w_reg[2];

  ao_load(in, 0, ty0, tx0, W, HW, tid, a_reg);
  {
    const float4* wsrc4 = (const float4*)wg;
    #pragma unroll
    for (int i = 0; i < 2; i++) {
      int e = tid + 192 * i;
      if (e < 288) w_reg[i] = wsrc4[e];
    }
  }
  ao_store(tid, a_reg, As[0]);
  {
    float4* wdst4 = (float4*)&Wg[0][0][0][0];
    #pragma unroll
    for (int i = 0; i < 2; i++) {
      int e = tid + 192 * i;
      if (e < 288) wdst4[e] = w_reg[i];
    }
  }
  __syncthreads();

  for (int k = 0; k < 32; k++) {
    const int kb = k & 1;
    const bool more = k < 31;
    if (more) {
      ao_load(in, (k + 1) * 8, ty0, tx0, W, HW, tid, a_reg);
      const float4* wsrc4 = (const float4*)(wg + (size_t)(k + 1) * 1152);
      #pragma unroll
      for (int i = 0; i < 2; i++) {
        int e = tid + 192 * i;
        if (e < 288) w_reg[i] = wsrc4[e];
      }
    }
    #pragma unroll 2
    for (int ci = 0; ci < 8; ci++) {
      #pragma unroll
      for (int ty = 0; ty < 3; ty++) {
        float a0 = As[kb][ci][y + ty][x + 0];
        float a1 = As[kb][ci][y + ty][x + 1];
        float a2 = As[kb][ci][y + ty][x + 2];
        #pragma unroll
        for (int tx = 0; tx < 3; tx++) {
          float av = (tx == 0) ? a0 : (tx == 1) ? a1 : a2;
          float4 w4 = *(const float4*)&Wg[kb][ci][ty * 3 + tx][4 * wv];
          acc0 = fmaf(av, w4.x, acc0);
          acc1 = fmaf(av, w4.y, acc1);
          acc2 = fmaf(av, w4.z, acc2);
        }
      }
    }
    if (more) {
      ao_store(tid, a_reg, As[kb ^ 1]);
      float4* wdst4 = (float4*)&Wg[kb ^ 1][0][0][0];
      #pragma unroll
      for (int i = 0; i < 2; i++) {
        int e = tid + 192 * i;
        if (e < 288) wdst4[e] = w_reg[i];
      }
      __syncthreads();
    }
  }
  const int oy = ty0 + y, ox = tx0 + x;
  if (oy < W && ox < W) {
    const int cell = oy * W + ox;
    const int aoff = pick5(lvl, 0, 57600, 72000, 75600, 76500);
    float* dst = args.dst[head];
    const float* bias = args.b[head];
    #pragma unroll
    for (int c = 0; c < 3; c++) {
      int co = co0 + 3 * wv + c;
      float v = ((c == 0) ? acc0 : (c == 1) ? acc1 : acc2) + bias[co];
      if (head == 0) {
        v = 1.f / (1.f + expf(-v));
        dst[aoff + cell * 9 + co] = v;
      } else {
        dst[(size_t)aoff * 4 + cell * 36 + co] = v;
      }
    }
  }
}

// ---------------- init / decode (unchanged) ----------------
__global__ void init_k(int* meta) {
  int i = blockIdx.x * 256 + threadIdx.x;
  if (i < 1 + NBKT) meta[i] = 0;
}

__global__ __launch_bounds__(256) void decode_k(const float* __restrict__ scores,
                                                const float* __restrict__ regs,
                                                float* cand_s, float4* cand_b,
                                                int* cand_n, int* meta) {
  int n = blockIdx.x * 256 + threadIdx.x;
  if (n >= N_ANCH) return;
  int lvl = 0;
  if (n >= 57600) lvl = 1;
  if (n >= 72000) lvl = 2;
  if (n >= 75600) lvl = 3;
  if (n >= 76500) lvl = 4;
  const int aoff = pick5(lvl, 0, 57600, 72000, 75600, 76500);
  const int W = 80 >> lvl;
  int r = n - aoff;
  int a = r % 9;
  int cell = r / 9;
  int x = cell % W, y = cell / W;
  double stride = (double)(8 << lvl);
  double base = (double)(32 << lvl);
  int si = a % 3, ri = a / 3;
  double s = (si == 0) ? 1.0 : (si == 1) ? 1.2599210498948731648 : 1.5874010519681994748;
  double ratio = (ri == 0) ? 0.5 : (ri == 1) ? 1.0 : 2.0;
  double ws0 = base * s;
  double area = ws0 * ws0;
  double w = sqrt(area / ratio);
  double h = w * ratio;
  double cx = ((double)x + 0.5) * stride;
  double cy = ((double)y + 0.5) * stride;
  float ax1 = (float)(cx - 0.5 * w);
  float ay1 = (float)(cy - 0.5 * h);
  float ax2 = (float)(cx + (w - 0.5 * w));
  float ay2 = (float)(cy + (h - 0.5 * h));
  float4 rg = ((const float4*)regs)[n];
  float aw = ax2 - ax1, ah = ay2 - ay1;
  float acx = ax1 + 0.5f * aw, acy = ay1 + 0.5f * ah;
  float pcx = acx + rg.x * 0.1f * aw;
  float pcy = acy + rg.y * 0.1f * ah;
  float pw = expf(rg.z * 0.2f) * aw;
  float ph = expf(rg.w * 0.2f) * ah;
  float x1 = pcx - 0.5f * pw, y1 = pcy - 0.5f * ph;
  float x2 = pcx + 0.5f * pw, y2 = pcy + 0.5f * ph;
  x1 = fminf(fmaxf(x1, 0.f), 640.f);
  y1 = fminf(fmaxf(y1, 0.f), 640.f);
  x2 = fminf(fmaxf(x2, 0.f), 640.f);
  y2 = fminf(fmaxf(y2, 0.f), 640.f);
  float sc = scores[n];
  if (sc > 0.05f) {
    int p = atomicAdd(&meta[0], 1);
    cand_s[p] = sc;
    cand_b[p] = make_float4(x1, y1, x2, y2);
    cand_n[p] = n;
    unsigned int sb = __float_as_uint(sc);
    int bk = (int)(sb >> 16) - (int)BBASE;
    bk = max(0, min(NBKT - 1, bk));
    atomicAdd(&meta[1 + bk], 1);
  }
}

// ---------------- sort-based exact greedy NMS (unchanged) ----------------
__global__ __launch_bounds__(1024) void nms2_k(const float* __restrict__ cs,
                                               const float4* __restrict__ cb,
                                               const int* __restrict__ cn,
                                               const int* __restrict__ meta,
                                               float* __restrict__ out) {
  __shared__ unsigned long long skey[SORT_N];
  __shared__ int sidx[SORT_N];
  __shared__ int suf[NBKT];
  __shared__ float kx1[300], ky1[300], kx2[300], ky2[300], kar[300];
  __shared__ int sh_i[8];
  const int tid = threadIdx.x;
  const int m = min(meta[0], N_ANCH);

  for (int b = tid; b < NBKT; b += 1024) suf[b] = meta[1 + b];
  __syncthreads();
  for (int off = 1; off < NBKT; off <<= 1) {
    int v0 = suf[tid] + ((tid + off < NBKT) ? suf[tid + off] : 0);
    __syncthreads();
    suf[tid] = v0;
    __syncthreads();
  }

  int nk = 0;
  unsigned long long hi64 = ~0ULL;
  int processed = 0;

  while (nk < 300 && processed < m) {
    int base = 0;
    if (hi64 != ~0ULL) {
      if (tid == 0) sh_i[4] = 0;
      __syncthreads();
      int c = 0;
      for (int j = tid; j < m; j += 1024) {
        unsigned long long K = ((unsigned long long)__float_as_uint(cs[j]) << 32) |
                               (unsigned int)(~cn[j]);
        if (K >= hi64) c++;
      }
      atomicAdd(&sh_i[4], c);
      __syncthreads();
      base = sh_i[4];
      __syncthreads();
    }
    if (tid == 0) sh_i[3] = NBKT + 1;
    __syncthreads();
    {
      int T = tid;
      unsigned long long lo =
          (T == 0) ? 0ULL : ((unsigned long long)(((unsigned)T + BBASE) << 16) << 32);
      int c = suf[T] - base;
      if (lo < hi64 && c >= 1 && c <= SORT_N) atomicMin(&sh_i[3], T);
    }
    __syncthreads();
    int T = sh_i[3];
    __syncthreads();
    unsigned long long lo64;
    if (T <= NBKT) {
      lo64 = (T == 0) ? 0ULL : ((unsigned long long)(((unsigned)T + BBASE) << 16) << 32);
    } else {
      unsigned long long L = 0, H = hi64;
      while (H - L > 1) {
        unsigned long long mid = L + ((H - L) >> 1);
        if (tid == 0) sh_i[4] = 0;
        __syncthreads();
        int c = 0;
        for (int j = tid; j < m; j += 1024) {
          unsigned long long K = ((unsigned long long)__float_as_uint(cs[j]) << 32) |
                                 (unsigned int)(~cn[j]);
          if (K >= mid && K < hi64) c++;
        }
        atomicAdd(&sh_i[4], c);
        __syncthreads();
        int cc = sh_i[4];
        __syncthreads();
        if (cc > SORT_N) L = mid; else H = mid;
      }
      lo64 = H;
    }
    if (tid == 0) sh_i[0] = 0;
    __syncthreads();
    for (int j = tid; j < m; j += 1024) {
      unsigned long long K = ((unsigned long long)__float_as_uint(cs[j]) << 32) |
                             (unsigned int)(~cn[j]);
      if (K >= lo64 && K < hi64) {
        int p = atomicAdd(&sh_i[0], 1);
        if (p < SORT_N) { skey[p] = K; sidx[p] = j; }
      }
    }
    __syncthreads();
    int bn = min(sh_i[0], SORT_N);
    __syncthreads();
    for (int p = bn + tid; p < SORT_N; p += 1024) { skey[p] = 0; sidx[p] = 0; }
    __syncthreads();
    for (int k = 2; k <= SORT_N; k <<= 1) {
      for (int jj = k >> 1; jj > 0; jj >>= 1) {
        for (int i = tid; i < SORT_N; i += 1024) {
          int l2 = i ^ jj;
          if (l2 > i) {
            unsigned long long a = skey[i], b2 = skey[l2];
            bool desc = ((i & k) == 0);
            if ((a < b2) == desc) {
              skey[i] = b2; skey[l2] = a;
              int t2 = sidx[i]; sidx[i] = sidx[l2]; sidx[l2] = t2;
            }
          }
        }
        __syncthreads();
      }
    }
    float4 pb0 = (bn > 0) ? cb[sidx[0]] : make_float4(0.f, 0.f, 0.f, 0.f);
    float4 pb1 = (bn > 1) ? cb[sidx[1]] : make_float4(0.f, 0.f, 0.f, 0.f);
    int pos = 0;
    while (pos < bn && nk < 300) {
      float4 c0 = pb0, c1 = pb1;
      const bool has1 = (pos + 1 < bn);
      unsigned long long K0 = skey[pos];
      unsigned long long K1 = has1 ? skey[pos + 1] : 0ULL;
      if (pos + 2 < bn) pb0 = cb[sidx[pos + 2]];
      if (pos + 3 < bn) pb1 = cb[sidx[pos + 3]];
      if (tid == 0) { sh_i[1] = 0; sh_i[2] = 0; }
      __syncthreads();
      float ar0 = (c0.z - c0.x) * (c0.w - c0.y);
      float ar1 = (c1.z - c1.x) * (c1.w - c1.y);
      if (tid < nk) {
        float qx1 = kx1[tid], qy1 = ky1[tid], qx2 = kx2[tid], qy2 = ky2[tid], qa = kar[tid];
        float xx1 = fmaxf(qx1, c0.x), yy1 = fmaxf(qy1, c0.y);
        float xx2 = fminf(qx2, c0.z), yy2 = fminf(qy2, c0.w);
        float inter = fmaxf(xx2 - xx1, 0.f) * fmaxf(yy2 - yy1, 0.f);
        if (inter / (ar0 + qa - inter + 1e-8f) > 0.5f) sh_i[1] = 1;
        if (has1) {
          float ux1 = fmaxf(qx1, c1.x), uy1 = fmaxf(qy1, c1.y);
          float ux2 = fminf(qx2, c1.z), uy2 = fminf(qy2, c1.w);
          float inter1 = fmaxf(ux2 - ux1, 0.f) * fmaxf(uy2 - uy1, 0.f);
          if (inter1 / (ar1 + qa - inter1 + 1e-8f) > 0.5f) sh_i[2] = 1;
        }
      }
      __syncthreads();
      bool k0 = (sh_i[1] == 0);
      float px1 = fmaxf(c0.x, c1.x), py1 = fmaxf(c0.y, c1.y);
      float px2 = fminf(c0.z, c1.z), py2 = fminf(c0.w, c1.w);
      float pint = fmaxf(px2 - px1, 0.f) * fmaxf(py2 - py1, 0.f);
      bool p01 = (pint / (ar1 + ar0 - pint + 1e-8f)) > 0.5f;
      bool k1 = has1 && (sh_i[2] == 0) && !(k0 && p01);
      if (k0) {
        if (tid == 0) {
          kx1[nk] = c0.x; ky1[nk] = c0.y; kx2[nk] = c0.z; ky2[nk] = c0.w; kar[nk] = ar0;
          out[nk] = __uint_as_float((unsigned int)(K0 >> 32));
          out[300 + nk] = 0.0f;
          out[600 + 4 * nk + 0] = c0.x;
          out[600 + 4 * nk + 1] = c0.y;
          out[600 + 4 * nk + 2] = c0.z;
          out[600 + 4 * nk + 3] = c0.w;
        }
        nk++;
      }
      if (nk < 300 && k1) {
        if (tid == 0) {
          kx1[nk] = c1.x; ky1[nk] = c1.y; kx2[nk] = c1.z; ky2[nk] = c1.w; kar[nk] = ar1;
          out[nk] = __uint_as_float((unsigned int)(K1 >> 32));
          out[300 + nk] = 0.0f;
          out[600 + 4 * nk + 0] = c1.x;
          out[600 + 4 * nk + 1] = c1.y;
          out[600 + 4 * nk + 2] = c1.z;
          out[600 + 4 * nk + 3] = c1.w;
        }
        nk++;
      }
      pos += 2;
    }
    processed = base + bn;
    hi64 = lo64;
  }
  __syncthreads();
  for (int r = nk + tid; r < 300; r += 1024) {
    out[r] = 0.f;
    out[300 + r] = -1.f;
    out[600 + 4 * r + 0] = 0.f;
    out[600 + 4 * r + 1] = 0.f;
    out[600 + 4 * r + 2] = 0.f;
    out[600 + 4 * r + 3] = 0.f;
  }
}

// ---------------- host ----------------
extern "C" void kernel_launch(void* const* d_in, const int* in_sizes, int n_in,
                              void* d_out, int out_size, void* d_ws, size_t ws_size,
                              hipStream_t stream) {
  (void)in_sizes; (void)n_in; (void)out_size; (void)ws_size;
  const float* feats[5];
  for (int ll = 0; ll < 5; ll++) feats[ll] = (const float*)d_in[1 + ll];
  const float* cls_w = (const float*)d_in[6];
  const float* cls_b = (const float*)d_in[7];
  const float* cls_ow = (const float*)d_in[8];
  const float* cls_ob = (const float*)d_in[9];
  const float* reg_w = (const float*)d_in[10];
  const float* reg_b = (const float*)d_in[11];
  const float* reg_ow = (const float*)d_in[12];
  const float* reg_ob = (const float*)d_in[13];

  static const int AOFF[5] = {0, 1638400, 2048000, 2150400, 2176000}; // 256*cumHW
  const size_t ACT = 2182400;  // fp32 activations per head
  const size_t PLH = 2182400;  // f16 elements per plane

  float* wsf = (float*)d_ws;
  float* ACCr = wsf;                       // reg fp32 accumulator / final reg acts (ACT)
  float* clsA = wsf + ACT;                 // cls fp32 ping (ACT)
  float* clsB = wsf + 2 * ACT;             // cls fp32 pong (ACT)
  f16* slotA = (f16*)(wsf + 3 * ACT);      // reg hi/lo planes (2*PLH f16 = ACT floats)
  f16* slotB = (f16*)(wsf + 4 * ACT);      // reg hi/lo planes (also feat pack)
  float* wt = wsf + 5 * ACT;               // cls re-laid weights: 4*2304*64 = 589824
  f16* wpkh = (f16*)(wsf + 5 * ACT + 589824);   // reg hi weights (589824 f16 = 294912 floats)
  f16* wpkl = (f16*)(wsf + 5 * ACT + 884736);   // reg lo weights
  unsigned short* zbuf = (unsigned short*)(wsf + 5 * ACT + 1179648);  // 16 floats
  float* scores = wsf + 5 * ACT + 1179664;
  float* regs = scores + 76736;
  float* cand_s = regs + 306912;
  float* cand_b = cand_s + 76736;
  int* cand_n = (int*)(cand_b + 306944);
  int* meta = cand_n + 76736;
  float* wt2o = (float*)(meta + 1032);

  FcvArgs fa;
  for (int ll = 0; ll < 5; ll++) fa.f[ll] = feats[ll];
  fa.hi = slotB;
  fa.lo = slotB + PLH;
  fa.zbuf = zbuf;
  featcvt_k<<<dim3(135, 8), dim3(256), 0, stream>>>(fa);
  wtro_k<<<dim3(9), dim3(256), 0, stream>>>(cls_ow, reg_ow, wt2o);

  float* clsBufs[2] = {clsA, clsB};
  for (int layer = 0; layer < 4; layer++) {
    // --- reg head: MFMA split-f16 path ---
    wsplit_k<<<dim3(2304), dim3(256), 0, stream>>>(reg_w + (size_t)layer * 589824, wpkh, wpkl);
    hipMemsetAsync(ACCr, 0, ACT * sizeof(float), stream);
    TrkArgs ta;
    if (layer == 0) {
      ta.in_hi = slotB;
      ta.in_lo = slotB + PLH;
    } else {
      f16* s = (layer & 1) ? slotA : slotB;
      ta.in_hi = s;
      ta.in_lo = s + PLH;
    }
    ta.w_hi = wpkh;
    ta.w_lo = wpkl;
    ta.acc = ACCr;
    ta.zbuf = (const f16*)zbuf;
    trunk_mm<<<dim3(296), dim3(256), 0, stream>>>(ta);
    EpiArgs ea;
    f16* outS = (layer & 1) ? slotB : slotA;  // L0->A, L1->B, L2->A, L3 in-place fp32
    ea.acc = ACCr;
    ea.bias = reg_b + layer * 256;
    ea.hi = outS;
    ea.lo = outS + PLH;
    ea.last = (layer == 3) ? 1 : 0;
    epi_k<<<dim3(135, 8), dim3(256), 0, stream>>>(ea);

    // --- cls head: baseline fp32 vector path (bit-exact vs passing baseline) ---
    WtrArgs wa;
    wa.src[0] = cls_w + (size_t)layer * 589824;
    wa.src[1] = wa.src[0];
    wa.dst = wt;
    wtr_k<<<dim3(32, 4, 1), dim3(256), 0, stream>>>(wa);
    TrunkArgs tra;
    tra.w[0] = wt;
    tra.w[1] = wt;
    tra.b[0] = cls_b + layer * 256;
    tra.b[1] = tra.b[0];
    for (int ll = 0; ll < 5; ll++) {
      tra.out[0][ll] = clsBufs[layer & 1] + AOFF[ll];
      tra.out[1][ll] = tra.out[0][ll];
      tra.in[0][ll] = (layer == 0) ? feats[ll]
                                   : (const float*)(clsBufs[(layer - 1) & 1] + AOFF[ll]);
      tra.in[1][ll] = tra.in[0][ll];
    }
    conv_trunk<<<dim3(74, 4, 1), dim3(256), 0, stream>>>(tra);
  }

  Out2Args oa;
  for (int ll = 0; ll < 5; ll++) {
    oa.in[0][ll] = clsB + AOFF[ll];
    oa.in[1][ll] = ACCr + AOFF[ll];
  }
  oa.w = wt2o;
  oa.b[0] = cls_ob;
  oa.b[1] = reg_ob;
  oa.dst[0] = scores;
  oa.dst[1] = regs;
  conv_out2<<<dim3(139, 5), dim3(192), 0, stream>>>(oa);

  init_k<<<dim3(5), dim3(256), 0, stream>>>(meta);
  decode_k<<<dim3((N_ANCH + 255) / 256), dim3(256), 0, stream>>>(scores, regs, cand_s,
                                                                 (float4*)cand_b, cand_n, meta);
  nms2_k<<<dim3(1), dim3(1024), 0, stream>>>(cand_s, (const float4*)cand_b, cand_n, meta,
                                             (float*)d_out);
}

// Round 5
// 1421.512 us; speedup vs baseline: 1.2147x; 1.2147x over previous
//
#include <hip/hip_runtime.h>
#include <math.h>

#define N_ANCH 76725
#define SORT_N 4096
#define NBKT 1024
#define BBASE 0x3D40u

typedef _Float16 f16;
typedef _Float16 f16x8 __attribute__((ext_vector_type(8)));
typedef float f32x4 __attribute__((ext_vector_type(4)));

__device__ __forceinline__ int pick5(int l, int a, int b, int c, int d, int e) {
  int r = a;
  if (l == 1) r = b;
  if (l == 2) r = c;
  if (l == 3) r = d;
  if (l == 4) r = e;
  return r;
}

// 64-position tiling (8x8): 139 tiles (conv_out2)
__device__ __forceinline__ void tile_to_level(int tile, int& lvl, int& t) {
  int l = 0;
  if (tile >= 100) l = 1;
  if (tile >= 125) l = 2;
  if (tile >= 134) l = 3;
  if (tile >= 138) l = 4;
  lvl = l;
  t = tile - pick5(l, 0, 100, 125, 134, 138);
}

// 64-linear-position tiling: 135 tiles (featcvt / epi)
__device__ __forceinline__ int tile64_lvl(int bx, int& t) {
  int l = 0;
  if (bx >= 100) l = 1;
  if (bx >= 125) l = 2;
  if (bx >= 132) l = 3;
  if (bx >= 134) l = 4;
  t = bx - pick5(l, 0, 100, 125, 132, 134);
  return l;
}

// fp32 -> f16 hi + (scaled by 2^12) f16 lo.  hi forced away from f16-denormal range.
__device__ __forceinline__ void split16(float v, f16& h, f16& l) {
  f16 hh = (f16)v;
  if (fabsf(v) < 6.103515625e-5f) hh = (f16)0.f;
  h = hh;
  l = (f16)((v - (float)hh) * 4096.f);
}

// async global->LDS, 16B per lane; dst wave-uniform base, lane i lands at dst+16*i
__device__ __forceinline__ void glds16h(const void* g, void* l) {
  __builtin_amdgcn_global_load_lds(
      (const __attribute__((address_space(1))) unsigned int*)g,
      (__attribute__((address_space(3))) unsigned int*)l, 16, 0, 0);
}

__device__ __forceinline__ void glds16(const float* g, float* l) {
  __builtin_amdgcn_global_load_lds(
      (const __attribute__((address_space(1))) unsigned int*)g,
      (__attribute__((address_space(3))) unsigned int*)l, 16, 0, 0);
}

// ---------------- feats fp32 NCHW -> packed [pos][ci] hi/lo f16 planes (reg path) ----------------
struct FcvArgs {
  const float* f[5];
  f16* hi;
  f16* lo;
  unsigned short* zbuf;
};

__global__ __launch_bounds__(256) void featcvt_k(FcvArgs a) {
  __shared__ float tile[32][65];
  int t;
  const int l = tile64_lvl(blockIdx.x, t);
  const int W = 80 >> l, HW = W * W;
  const int p0 = t * 64;
  const int apos = pick5(l, 0, 6400, 8000, 8400, 8500);
  const int ci0 = blockIdx.y * 32;
  const int tid = threadIdx.x;
  if (blockIdx.x == 0 && blockIdx.y == 0 && tid < 32) a.zbuf[tid] = 0;
  const float* __restrict__ src = a.f[l];
  #pragma unroll
  for (int i = 0; i < 8; i++) {
    const int j = tid + 256 * i;
    const int ci = j >> 6, p = j & 63;
    float v = 0.f;
    if (p0 + p < HW) v = src[(ci0 + ci) * HW + p0 + p];
    tile[ci][p] = v;
  }
  __syncthreads();
  const int p_l = tid >> 2, cq = tid & 3;
  if (p0 + p_l < HW) {
    union { f16 h[8]; uint4 v; } uh, ul;
    #pragma unroll
    for (int u = 0; u < 8; u++) split16(tile[cq * 8 + u][p_l], uh.h[u], ul.h[u]);
    const size_t base = (size_t)(apos + p0 + p_l) * 256 + ci0 + cq * 8;
    *(uint4*)(a.hi + base) = uh.v;
    *(uint4*)(a.lo + base) = ul.v;
  }
}

// ---------------- reg trunk weights -> hi/lo f16, layout [c=tap*8+ciq][co 256][k 32] ----------------
__global__ __launch_bounds__(256) void wsplit_k(const float* __restrict__ src,
                                                f16* __restrict__ whi,
                                                f16* __restrict__ wlo) {
  const int e = blockIdx.x * 256 + threadIdx.x;  // 0..589823
  const int k = e & 31, co = (e >> 5) & 255, c = e >> 13;
  const int tap = c >> 3, ciq = c & 7;
  const int ci = ciq * 32 + k;
  const float v = src[((size_t)co * 256 + ci) * 9 + tap];
  f16 h, lo;
  split16(v, h, lo);
  whi[e] = h;
  wlo[e] = lo;
}

// ---------------- cls weight re-layout (baseline path) ----------------
struct WtrArgs {
  const float* src[2];
  float* dst;           // wt2: [cog][2304][64]
};

__global__ __launch_bounds__(256) void wtr_k(WtrArgs a) {
  __shared__ float tile[72][65];
  const int r0 = blockIdx.x * 72;   // 32 groups
  const int cog = blockIdx.y;       // 4 groups of 64 co
  const int co0 = cog * 64;
  const int head = blockIdx.z;
  const float* __restrict__ src = a.src[head];
  float* __restrict__ dst = a.dst + ((size_t)(head * 4 + cog) * 2304 + r0) * 64;
  const int tid = threadIdx.x;
  #pragma unroll
  for (int i = 0; i < 18; i++) {
    int e = tid + 256 * i;  // < 4608
    int co = e / 72;
    int r = e - co * 72;
    tile[r][co] = src[(size_t)(co0 + co) * 2304 + r0 + r];
  }
  __syncthreads();
  #pragma unroll
  for (int i = 0; i < 18; i++) {
    int e = tid + 256 * i;
    int r = e >> 6;
    int co = e & 63;
    dst[(size_t)r * 64 + co] = tile[r][co];
  }
}

// ---------------- helpers for fp32 conv body (bit-exact baseline math) ----------------
__device__ __forceinline__ void a_load(const float* __restrict__ in, int ci0,
                                       int ty0, int tx0, int W, int HW, int tid,
                                       float a_reg[6]) {
  const float* inc = in + ci0 * HW;
  #pragma unroll
  for (int i = 0; i < 6; i++) {
    int e = tid + 256 * i;
    float v = 0.f;
    if (e < 1440) {
      int ci = e / 180;
      int rem = e - ci * 180;
      int yy = rem / 10;
      int xx = rem - yy * 10;
      int gy = ty0 + yy - 1, gx = tx0 + xx - 1;
      if ((unsigned)gy < (unsigned)W && (unsigned)gx < (unsigned)W)
        v = inc[ci * HW + gy * W + gx];
    }
    a_reg[i] = v;
  }
}

__device__ __forceinline__ void a_store(int tid, const float a_reg[6],
                                        float As[8][18][12]) {
  #pragma unroll
  for (int i = 0; i < 6; i++) {
    int e = tid + 256 * i;
    if (e < 1440) {
      int ci = e / 180;
      int rem = e - ci * 180;
      int yy = rem / 10;
      int xx = rem - yy * 10;
      As[ci][yy][xx] = a_reg[i];
    }
  }
}

__device__ __forceinline__ void stage_w(const float* __restrict__ wchunk,
                                        float* wbuf, int wv, int lane) {
  #pragma unroll
  for (int i = 0; i < 5; i++) {
    int j = wv + 4 * i;           // wave-uniform
    if (j < 18) glds16(wchunk + j * 256 + lane * 4, wbuf + j * 256);
  }
}

// ---------------- FUSED per-layer trunk: blocks 0..295 = reg MFMA, 296..591 = cls fp32 ----------------
struct FusedArgs {
  const f16* in_hi;
  const f16* in_lo;
  const f16* w_hi;
  const f16* w_lo;
  float* acc0;          // reg K-half 0
  float* acc1;          // reg K-half 1
  const f16* zbuf;
  const float* cin[5];  // cls inputs per level
  float* cout[5];       // cls outputs per level
  const float* cw;      // re-laid cls weights
  const float* cb;      // cls bias
};

__global__ __launch_bounds__(256, 2) void fused_trunk(FusedArgs a) {
  __shared__ __align__(16) char smem[65536];
  const int bx = blockIdx.x;
  const int tid = threadIdx.x;
  if (bx < 296) {
    // ===== reg head: MFMA split-f16 implicit GEMM, 128co x 128pos, K-split-2 =====
    f16 (*Xh)[4096] = (f16 (*)[4096])(smem);
    f16 (*Xl)[4096] = (f16 (*)[4096])(smem + 16384);
    f16 (*Wh)[4096] = (f16 (*)[4096])(smem + 32768);
    f16 (*Wl)[4096] = (f16 (*)[4096])(smem + 49152);
    const int combo = bx & 3, tl = bx >> 2;
    const int cog = combo >> 1, kh = combo & 1;
    int l = 0;
    if (tl >= 50) l = 1;
    if (tl >= 65) l = 2;
    if (tl >= 71) l = 3;
    if (tl >= 73) l = 4;
    const int t = tl - pick5(l, 0, 50, 65, 71, 73);
    const int W = 80 >> l, HW = W * W, tX = (W + 7) >> 3;
    const int ty0 = (t / tX) * 16, tx0 = (t % tX) * 8;
    const int apos = pick5(l, 0, 6400, 8000, 8400, 8500);
    const int co0 = cog * 128;
    const int lane = tid & 63, wv = tid >> 6;
    const int ln15 = lane & 15, lh = lane >> 4;
    const int wco = wv & 1, wpos = wv >> 1;
    const f16* __restrict__ ihi = a.in_hi;
    const f16* __restrict__ ilo = a.in_lo;
    const f16* __restrict__ whi = a.w_hi;
    const f16* __restrict__ wlo = a.w_lo;

    f32x4 accA[4][4] = {};
    f32x4 accB[4][4] = {};

    auto stage = [&](int c, int buf) {
      const int tap = c >> 3, ciq = c & 7;
      const int dy = tap / 3 - 1, dx = tap - (tap / 3) * 3 - 1;
      #pragma unroll
      for (int i = 0; i < 2; i++) {
        const int s = (wv * 2 + i) * 64 + lane;
        const int pos = s >> 2, kq = s & 3;
        const int kqd = kq ^ (pos & 3);
        const int gy = ty0 + (pos >> 3) + dy, gx = tx0 + (pos & 7) + dx;
        const bool v = (unsigned)gy < (unsigned)W && (unsigned)gx < (unsigned)W;
        const int off = (apos + gy * W + gx) * 256 + ciq * 32 + kqd * 8;
        glds16h(v ? (const void*)(ihi + off) : (const void*)a.zbuf, &Xh[buf][(wv * 2 + i) * 512]);
        glds16h(v ? (const void*)(ilo + off) : (const void*)a.zbuf, &Xl[buf][(wv * 2 + i) * 512]);
      }
      const f16* wh = whi + (size_t)c * 8192;
      const f16* wl = wlo + (size_t)c * 8192;
      #pragma unroll
      for (int i = 0; i < 2; i++) {
        const int s = (wv * 2 + i) * 64 + lane;
        const int col = s >> 2, kq = s & 3;
        const int kqd = kq ^ (col & 3);
        const int off = (co0 + col) * 32 + kqd * 8;
        glds16h(wh + off, &Wh[buf][(wv * 2 + i) * 512]);
        glds16h(wl + off, &Wl[buf][(wv * 2 + i) * 512]);
      }
    };

    const int c0 = kh * 36;
    stage(c0, 0);
    __syncthreads();
    for (int j = 0; j < 36; j++) {
      const int b = j & 1;
      if (j < 35) stage(c0 + j + 1, b ^ 1);
      const int slot = (lh ^ (ln15 & 3)) * 8;
      const int aro = (wco * 64 + ln15) * 32 + slot;
      const int bro = (wpos * 64 + ln15) * 32 + slot;
      f16x8 ah[4], al[4];
      #pragma unroll
      for (int mi = 0; mi < 4; mi++) {
        ah[mi] = *(const f16x8*)&Wh[b][aro + mi * 512];
        al[mi] = *(const f16x8*)&Wl[b][aro + mi * 512];
      }
      #pragma unroll
      for (int ni = 0; ni < 4; ni++) {
        const f16x8 bhv = *(const f16x8*)&Xh[b][bro + ni * 512];
        const f16x8 blv = *(const f16x8*)&Xl[b][bro + ni * 512];
        #pragma unroll
        for (int mi = 0; mi < 4; mi++) {
          accA[mi][ni] = __builtin_amdgcn_mfma_f32_16x16x32_f16(ah[mi], bhv, accA[mi][ni], 0, 0, 0);
          accB[mi][ni] = __builtin_amdgcn_mfma_f32_16x16x32_f16(ah[mi], blv, accB[mi][ni], 0, 0, 0);
          accB[mi][ni] = __builtin_amdgcn_mfma_f32_16x16x32_f16(al[mi], bhv, accB[mi][ni], 0, 0, 0);
        }
      }
      __syncthreads();
    }

    const int aoffF = pick5(l, 0, 1638400, 2048000, 2150400, 2176000);
    float* __restrict__ dst = (kh == 0 ? a.acc0 : a.acc1) + aoffF;
    #pragma unroll
    for (int ni = 0; ni < 4; ni++) {
      const int pos = wpos * 64 + ni * 16 + ln15;
      const int gy = ty0 + (pos >> 3), gx = tx0 + (pos & 7);
      if (gy < W && gx < W) {
        #pragma unroll
        for (int mi = 0; mi < 4; mi++) {
          const int co = co0 + wco * 64 + mi * 16 + lh * 4;
          float* d = dst + (size_t)co * HW + gy * W + gx;
          #pragma unroll
          for (int r = 0; r < 4; r++)
            d[(size_t)r * HW] = accA[mi][ni][r] + accB[mi][ni][r] * 2.44140625e-4f;
        }
      }
    }
  } else {
    // ===== cls head: baseline fp32 vector conv (bit-exact chains) =====
    float (*As)[8][18][12] = (float (*)[8][18][12])(smem);         // [2][8][18][12]
    float (*Ws)[72][64] = (float (*)[72][64])(smem + 13824);       // [2][72][64]
    const int idx = bx - 296;
    const int cog = idx & 3;
    const int tl = idx >> 2;    // 0..73
    int l = 0;
    if (tl >= 50) l = 1;
    if (tl >= 65) l = 2;
    if (tl >= 71) l = 3;
    if (tl >= 73) l = 4;
    const int lvl = l;
    const int t = tl - pick5(l, 0, 50, 65, 71, 73);
    const int W = 80 >> lvl;
    const int HW = W * W;
    const int tX = (W + 7) >> 3;
    const int ty0 = (t / tX) * 16, tx0 = (t % tX) * 8;
    const int co0 = cog << 6;
    const float* __restrict__ in = a.cin[lvl];
    float* __restrict__ out = a.cout[lvl];
    const float* __restrict__ wsrc = a.cw + (size_t)cog * 2304 * 64;
    const int lane = tid & 63, wv = tid >> 6;
    const int cop = tid & 15;
    const int ry = tid >> 4;
    const int co_sub = cop << 2;
    float acc[8][4] = {};
    float a_reg[6];

    stage_w(wsrc, &Ws[0][0][0], wv, lane);
    a_load(in, 0, ty0, tx0, W, HW, tid, a_reg);
    a_store(tid, a_reg, As[0]);
    __syncthreads();

    for (int k = 0; k < 32; k++) {
      const int kb = k & 1;
      const bool more = k < 31;
      if (more) {
        stage_w(wsrc + (size_t)(k + 1) * 4608, &Ws[kb ^ 1][0][0], wv, lane);
        a_load(in, (k + 1) * 8, ty0, tx0, W, HW, tid, a_reg);
      }
      #pragma unroll 2
      for (int ci = 0; ci < 8; ci++) {
        #pragma unroll
        for (int ty = 0; ty < 3; ty++) {
          const float* ar = &As[kb][ci][ry + ty][0];
          float4 a0 = *(const float4*)ar;
          float4 a1 = *(const float4*)(ar + 4);
          float2 a2 = *(const float2*)(ar + 8);
          float av[10] = {a0.x, a0.y, a0.z, a0.w, a1.x, a1.y, a1.z, a1.w, a2.x, a2.y};
          #pragma unroll
          for (int tx = 0; tx < 3; tx++) {
            const float* wr = &Ws[kb][ci * 9 + ty * 3 + tx][co_sub];
            float4 wvv = *(const float4*)wr;
            #pragma unroll
            for (int p = 0; p < 8; p++) {
              acc[p][0] = fmaf(av[tx + p], wvv.x, acc[p][0]);
              acc[p][1] = fmaf(av[tx + p], wvv.y, acc[p][1]);
              acc[p][2] = fmaf(av[tx + p], wvv.z, acc[p][2]);
              acc[p][3] = fmaf(av[tx + p], wvv.w, acc[p][3]);
            }
          }
        }
      }
      if (more) {
        a_store(tid, a_reg, As[kb ^ 1]);
        __syncthreads();
      }
    }
    const float4 bias = *(const float4*)&a.cb[co0 + co_sub];
    const int oy = ty0 + ry;
    if (oy < W) {
      #pragma unroll
      for (int p = 0; p < 8; p++) {
        int ox = tx0 + p;
        if (ox < W) {
          int base = oy * W + ox;
          out[(co0 + co_sub + 0) * HW + base] = fmaxf(acc[p][0] + bias.x, 0.f);
          out[(co0 + co_sub + 1) * HW + base] = fmaxf(acc[p][1] + bias.y, 0.f);
          out[(co0 + co_sub + 2) * HW + base] = fmaxf(acc[p][2] + bias.z, 0.f);
          out[(co0 + co_sub + 3) * HW + base] = fmaxf(acc[p][3] + bias.w, 0.f);
        }
      }
    }
  }
}

// ---------------- reg per-layer epilogue: sum K-halves, bias+relu, re-split ----------------
struct EpiArgs {
  float* a0;            // K-half 0 (also in-place fp32 dst for last layer)
  const float* a1;      // K-half 1
  const float* bias;
  f16* hi;
  f16* lo;
  int last;
};

__global__ __launch_bounds__(256) void epi_k(EpiArgs a) {
  __shared__ float tile[32][65];
  int t;
  const int l = tile64_lvl(blockIdx.x, t);
  const int W = 80 >> l, HW = W * W;
  const int p0 = t * 64;
  const int apos = pick5(l, 0, 6400, 8000, 8400, 8500);
  const int ci0 = blockIdx.y * 32;
  const int tid = threadIdx.x;
  float* __restrict__ s0 = a.a0 + (size_t)apos * 256;
  const float* __restrict__ s1 = a.a1 + (size_t)apos * 256;
  const float* __restrict__ bias = a.bias;
  #pragma unroll
  for (int i = 0; i < 8; i++) {
    const int j = tid + 256 * i;
    const int ci = j >> 6, p = j & 63;
    float v = 0.f;
    if (p0 + p < HW) {
      const size_t off = (size_t)(ci0 + ci) * HW + p0 + p;
      float x = s0[off];
      float y = s1[off];
      v = x + y;
    }
    tile[ci][p] = fmaxf(v + bias[ci0 + ci], 0.f);
  }
  __syncthreads();
  if (a.last) {
    #pragma unroll
    for (int i = 0; i < 8; i++) {
      const int j = tid + 256 * i;
      const int ci = j >> 6, p = j & 63;
      if (p0 + p < HW) s0[(size_t)(ci0 + ci) * HW + p0 + p] = tile[ci][p];
    }
  } else {
    const int p_l = tid >> 2, cq = tid & 3;
    if (p0 + p_l < HW) {
      union { f16 h[8]; uint4 v; } uh, ul;
      #pragma unroll
      for (int u = 0; u < 8; u++) split16(tile[cq * 8 + u][p_l], uh.h[u], ul.h[u]);
      const size_t base = (size_t)(apos + p0 + p_l) * 256 + ci0 + cq * 8;
      *(uint4*)(a.hi + base) = uh.v;
      *(uint4*)(a.lo + base) = ul.v;
    }
  }
}

// ---------------- output-conv weight transpose ----------------
struct Out2Args {
  const float* in[2][5];
  const float* w;
  const float* b[2];
  float* dst[2];
};

__global__ __launch_bounds__(256) void wtro_k(const float* __restrict__ cls_ow,
                                              const float* __restrict__ reg_ow,
                                              float* __restrict__ dst) {
  int r = blockIdx.x * 256 + threadIdx.x;   // 0..2303
  if (r >= 2304) return;
  for (int g = 0; g < 5; g++) {
    #pragma unroll
    for (int s = 0; s < 16; s++) {
      int w = s >> 2, c = s & 3;
      float v = 0.f;
      if (w < 3 && c < 3) {
        int cl = 3 * w + c;
        v = (g == 0) ? cls_ow[(size_t)cl * 2304 + r]
                     : reg_ow[(size_t)((g - 1) * 9 + cl) * 2304 + r];
      }
      dst[((size_t)g * 2304 + r) * 16 + s] = v;
    }
  }
}

// ---------------- fused output convs (unchanged) ----------------
__device__ __forceinline__ void ao_load(const float* __restrict__ in, int ci0,
                                        int ty0, int tx0, int W, int HW, int tid,
                                        float a_reg[5]) {
  const float* inc = in + ci0 * HW;
  #pragma unroll
  for (int i = 0; i < 5; i++) {
    int e = tid + 192 * i;
    float v = 0.f;
    if (e < 800) {
      int ci = e / 100;
      int rem = e - ci * 100;
      int yy = rem / 10;
      int xx = rem - yy * 10;
      int gy = ty0 + yy - 1, gx = tx0 + xx - 1;
      if ((unsigned)gy < (unsigned)W && (unsigned)gx < (unsigned)W)
        v = inc[ci * HW + gy * W + gx];
    }
    a_reg[i] = v;
  }
}

__device__ __forceinline__ void ao_store(int tid, const float a_reg[5],
                                         float As[8][10][12]) {
  #pragma unroll
  for (int i = 0; i < 5; i++) {
    int e = tid + 192 * i;
    if (e < 800) {
      int ci = e / 100;
      int rem = e - ci * 100;
      int yy = rem / 10;
      int xx = rem - yy * 10;
      As[ci][yy][xx] = a_reg[i];
    }
  }
}

__global__ __launch_bounds__(192) void conv_out2(Out2Args args) {
  __shared__ float As[2][8][10][12];
  __shared__ __align__(16) float Wg[2][8][9][16];
  int lvl, t;
  tile_to_level(blockIdx.x, lvl, t);
  const int g = blockIdx.y;
  const int head = (g == 0) ? 0 : 1;
  const int co0 = (g == 0) ? 0 : (g - 1) * 9;
  const int W = 80 >> lvl;
  const int HW = W * W;
  const int tX = (W + 7) >> 3;
  const int ty0 = (t / tX) * 8, tx0 = (t % tX) * 8;
  const float* __restrict__ in = args.in[head][lvl];
  const float* __restrict__ wg = args.w + (size_t)g * 2304 * 16;
  const int tid = threadIdx.x;
  const int wv = tid >> 6;
  const int lane = tid & 63;
  const int y = lane >> 3, x = lane & 7;
  float acc0 = 0.f, acc1 = 0.f, acc2 = 0.f;
  float a_reg[5];
  float4 w_reg[2];

  ao_load(in, 0, ty0, tx0, W, HW, tid, a_reg);
  {
    const float4* wsrc4 = (const float4*)wg;
    #pragma unroll
    for (int i = 0; i < 2; i++) {
      int e = tid + 192 * i;
      if (e < 288) w_reg[i] = wsrc4[e];
    }
  }
  ao_store(tid, a_reg, As[0]);
  {
    float4* wdst4 = (float4*)&Wg[0][0][0][0];
    #pragma unroll
    for (int i = 0; i < 2; i++) {
      int e = tid + 192 * i;
      if (e < 288) wdst4[e] = w_reg[i];
    }
  }
  __syncthreads();

  for (int k = 0; k < 32; k++) {
    const int kb = k & 1;
    const bool more = k < 31;
    if (more) {
      ao_load(in, (k + 1) * 8, ty0, tx0, W, HW, tid, a_reg);
      const float4* wsrc4 = (const float4*)(wg + (size_t)(k + 1) * 1152);
      #pragma unroll
      for (int i = 0; i < 2; i++) {
        int e = tid + 192 * i;
        if (e < 288) w_reg[i] = wsrc4[e];
      }
    }
    #pragma unroll 2
    for (int ci = 0; ci < 8; ci++) {
      #pragma unroll
      for (int ty = 0; ty < 3; ty++) {
        float a0 = As[kb][ci][y + ty][x + 0];
        float a1 = As[kb][ci][y + ty][x + 1];
        float a2 = As[kb][ci][y + ty][x + 2];
        #pragma unroll
        for (int tx = 0; tx < 3; tx++) {
          float av = (tx == 0) ? a0 : (tx == 1) ? a1 : a2;
          float4 w4 = *(const float4*)&Wg[kb][ci][ty * 3 + tx][4 * wv];
          acc0 = fmaf(av, w4.x, acc0);
          acc1 = fmaf(av, w4.y, acc1);
          acc2 = fmaf(av, w4.z, acc2);
        }
      }
    }
    if (more) {
      ao_store(tid, a_reg, As[kb ^ 1]);
      float4* wdst4 = (float4*)&Wg[kb ^ 1][0][0][0];
      #pragma unroll
      for (int i = 0; i < 2; i++) {
        int e = tid + 192 * i;
        if (e < 288) wdst4[e] = w_reg[i];
      }
      __syncthreads();
    }
  }
  const int oy = ty0 + y, ox = tx0 + x;
  if (oy < W && ox < W) {
    const int cell = oy * W + ox;
    const int aoff = pick5(lvl, 0, 57600, 72000, 75600, 76500);
    float* dst = args.dst[head];
    const float* bias = args.b[head];
    #pragma unroll
    for (int c = 0; c < 3; c++) {
      int co = co0 + 3 * wv + c;
      float v = ((c == 0) ? acc0 : (c == 1) ? acc1 : acc2) + bias[co];
      if (head == 0) {
        v = 1.f / (1.f + expf(-v));
        dst[aoff + cell * 9 + co] = v;
      } else {
        dst[(size_t)aoff * 4 + cell * 36 + co] = v;
      }
    }
  }
}

// ---------------- init / decode (unchanged) ----------------
__global__ void init_k(int* meta) {
  int i = blockIdx.x * 256 + threadIdx.x;
  if (i < 1 + NBKT) meta[i] = 0;
}

__global__ __launch_bounds__(256) void decode_k(const float* __restrict__ scores,
                                                const float* __restrict__ regs,
                                                float* cand_s, float4* cand_b,
                                                int* cand_n, int* meta) {
  int n = blockIdx.x * 256 + threadIdx.x;
  if (n >= N_ANCH) return;
  int lvl = 0;
  if (n >= 57600) lvl = 1;
  if (n >= 72000) lvl = 2;
  if (n >= 75600) lvl = 3;
  if (n >= 76500) lvl = 4;
  const int aoff = pick5(lvl, 0, 57600, 72000, 75600, 76500);
  const int W = 80 >> lvl;
  int r = n - aoff;
  int a = r % 9;
  int cell = r / 9;
  int x = cell % W, y = cell / W;
  double stride = (double)(8 << lvl);
  double base = (double)(32 << lvl);
  int si = a % 3, ri = a / 3;
  double s = (si == 0) ? 1.0 : (si == 1) ? 1.2599210498948731648 : 1.5874010519681994748;
  double ratio = (ri == 0) ? 0.5 : (ri == 1) ? 1.0 : 2.0;
  double ws0 = base * s;
  double area = ws0 * ws0;
  double w = sqrt(area / ratio);
  double h = w * ratio;
  double cx = ((double)x + 0.5) * stride;
  double cy = ((double)y + 0.5) * stride;
  float ax1 = (float)(cx - 0.5 * w);
  float ay1 = (float)(cy - 0.5 * h);
  float ax2 = (float)(cx + (w - 0.5 * w));
  float ay2 = (float)(cy + (h - 0.5 * h));
  float4 rg = ((const float4*)regs)[n];
  float aw = ax2 - ax1, ah = ay2 - ay1;
  float acx = ax1 + 0.5f * aw, acy = ay1 + 0.5f * ah;
  float pcx = acx + rg.x * 0.1f * aw;
  float pcy = acy + rg.y * 0.1f * ah;
  float pw = expf(rg.z * 0.2f) * aw;
  float ph = expf(rg.w * 0.2f) * ah;
  float x1 = pcx - 0.5f * pw, y1 = pcy - 0.5f * ph;
  float x2 = pcx + 0.5f * pw, y2 = pcy + 0.5f * ph;
  x1 = fminf(fmaxf(x1, 0.f), 640.f);
  y1 = fminf(fmaxf(y1, 0.f), 640.f);
  x2 = fminf(fmaxf(x2, 0.f), 640.f);
  y2 = fminf(fmaxf(y2, 0.f), 640.f);
  float sc = scores[n];
  if (sc > 0.05f) {
    int p = atomicAdd(&meta[0], 1);
    cand_s[p] = sc;
    cand_b[p] = make_float4(x1, y1, x2, y2);
    cand_n[p] = n;
    unsigned int sb = __float_as_uint(sc);
    int bk = (int)(sb >> 16) - (int)BBASE;
    bk = max(0, min(NBKT - 1, bk));
    atomicAdd(&meta[1 + bk], 1);
  }
}

// ---------------- sort-based exact greedy NMS with chunked suppression masks ----------------
__global__ __launch_bounds__(1024) void nms2_k(const float* __restrict__ cs,
                                               const float4* __restrict__ cb,
                                               const int* __restrict__ cn,
                                               const int* __restrict__ meta,
                                               float* __restrict__ out) {
  __shared__ unsigned long long skey[SORT_N];   // reused as chunk scratch post-sort
  __shared__ int sidx[SORT_N];
  __shared__ int suf[NBKT];
  __shared__ float kx1[300], ky1[300], kx2[300], ky2[300], kar[300];
  __shared__ int sh_i[8];
  const int tid = threadIdx.x;
  const int m = min(meta[0], N_ANCH);

  for (int b = tid; b < NBKT; b += 1024) suf[b] = meta[1 + b];
  __syncthreads();
  for (int off = 1; off < NBKT; off <<= 1) {
    int v0 = suf[tid] + ((tid + off < NBKT) ? suf[tid + off] : 0);
    __syncthreads();
    suf[tid] = v0;
    __syncthreads();
  }

  int nk = 0;
  unsigned long long hi64 = ~0ULL;
  int processed = 0;

  while (nk < 300 && processed < m) {
    int base = 0;
    if (hi64 != ~0ULL) {
      if (tid == 0) sh_i[4] = 0;
      __syncthreads();
      int c = 0;
      for (int j = tid; j < m; j += 1024) {
        unsigned long long K = ((unsigned long long)__float_as_uint(cs[j]) << 32) |
                               (unsigned int)(~cn[j]);
        if (K >= hi64) c++;
      }
      atomicAdd(&sh_i[4], c);
      __syncthreads();
      base = sh_i[4];
      __syncthreads();
    }
    if (tid == 0) sh_i[3] = NBKT + 1;
    __syncthreads();
    {
      int T = tid;
      unsigned long long lo =
          (T == 0) ? 0ULL : ((unsigned long long)(((unsigned)T + BBASE) << 16) << 32);
      int c = suf[T] - base;
      if (lo < hi64 && c >= 1 && c <= SORT_N) atomicMin(&sh_i[3], T);
    }
    __syncthreads();
    int T = sh_i[3];
    __syncthreads();
    unsigned long long lo64;
    if (T <= NBKT) {
      lo64 = (T == 0) ? 0ULL : ((unsigned long long)(((unsigned)T + BBASE) << 16) << 32);
    } else {
      unsigned long long L = 0, H = hi64;
      while (H - L > 1) {
        unsigned long long mid = L + ((H - L) >> 1);
        if (tid == 0) sh_i[4] = 0;
        __syncthreads();
        int c = 0;
        for (int j = tid; j < m; j += 1024) {
          unsigned long long K = ((unsigned long long)__float_as_uint(cs[j]) << 32) |
                                 (unsigned int)(~cn[j]);
          if (K >= mid && K < hi64) c++;
        }
        atomicAdd(&sh_i[4], c);
        __syncthreads();
        int cc = sh_i[4];
        __syncthreads();
        if (cc > SORT_N) L = mid; else H = mid;
      }
      lo64 = H;
    }
    if (tid == 0) sh_i[0] = 0;
    __syncthreads();
    for (int j = tid; j < m; j += 1024) {
      unsigned long long K = ((unsigned long long)__float_as_uint(cs[j]) << 32) |
                             (unsigned int)(~cn[j]);
      if (K >= lo64 && K < hi64) {
        int p = atomicAdd(&sh_i[0], 1);
        if (p < SORT_N) { skey[p] = K; sidx[p] = j; }
      }
    }
    __syncthreads();
    int bn = min(sh_i[0], SORT_N);
    __syncthreads();
    for (int p = bn + tid; p < SORT_N; p += 1024) { skey[p] = 0; sidx[p] = 0; }
    __syncthreads();
    for (int k = 2; k <= SORT_N; k <<= 1) {
      for (int jj = k >> 1; jj > 0; jj >>= 1) {
        for (int i = tid; i < SORT_N; i += 1024) {
          int l2 = i ^ jj;
          if (l2 > i) {
            unsigned long long a = skey[i], b2 = skey[l2];
            bool desc = ((i & k) == 0);
            if ((a < b2) == desc) {
              skey[i] = b2; skey[l2] = a;
              int t2 = sidx[i]; sidx[i] = sidx[l2]; sidx[l2] = t2;
            }
          }
        }
        __syncthreads();
      }
    }
    // ---- chunked exact greedy: suppressed-by-kept flags + within-chunk masks ----
    {
      char* pool = (char*)skey;   // skey contents dead after sort (order lives in sidx)
      float* cx1 = (float*)pool;
      float* cy1 = cx1 + 256;
      float* cx2 = cy1 + 256;
      float* cy2 = cx2 + 256;
      float* car = cy2 + 256;
      int* sup = (int*)(car + 256);
      unsigned long long* msk = (unsigned long long*)(pool + 6144);  // [256][4]
      int cpos = 0;
      while (cpos < bn && nk < 300) {
        const int cl = min(256, bn - cpos);
        if (tid < 256) sup[tid] = 0;
        if (tid < cl) {
          float4 b = cb[sidx[cpos + tid]];
          cx1[tid] = b.x; cy1[tid] = b.y; cx2[tid] = b.z; cy2[tid] = b.w;
          car[tid] = (b.z - b.x) * (b.w - b.y);
        }
        __syncthreads();
        {
          const int i = tid >> 2, q = tid & 3;
          if (i < cl) {
            const float bx1 = cx1[i], by1 = cy1[i], bx2 = cx2[i], by2 = cy2[i], ba = car[i];
            int flag = 0;
            for (int k2 = q; k2 < nk; k2 += 4) {
              float xx1 = fmaxf(kx1[k2], bx1), yy1 = fmaxf(ky1[k2], by1);
              float xx2 = fminf(kx2[k2], bx2), yy2 = fminf(ky2[k2], by2);
              float inter = fmaxf(xx2 - xx1, 0.f) * fmaxf(yy2 - yy1, 0.f);
              if (inter / (ba + kar[k2] - inter + 1e-8f) > 0.5f) { flag = 1; break; }
            }
            if (flag) atomicOr(&sup[i], 1);
          }
        }
        {
          const int i = tid >> 2, w = tid & 3;
          unsigned long long bits = 0ull;
          if (i < cl) {
            const float ax1 = cx1[i], ay1 = cy1[i], ax2 = cx2[i], ay2 = cy2[i], aa = car[i];
            const int j0 = w * 64;
            for (int jj = 0; jj < 64; jj++) {
              const int j2 = j0 + jj;
              if (j2 > i && j2 < cl) {
                float xx1 = fmaxf(ax1, cx1[j2]), yy1 = fmaxf(ay1, cy1[j2]);
                float xx2 = fminf(ax2, cx2[j2]), yy2 = fminf(ay2, cy2[j2]);
                float inter = fmaxf(xx2 - xx1, 0.f) * fmaxf(yy2 - yy1, 0.f);
                if (inter / (car[j2] + aa - inter + 1e-8f) > 0.5f) bits |= (1ull << jj);
              }
            }
          }
          msk[(tid >> 2) * 4 + (tid & 3)] = bits;
        }
        __syncthreads();
        if (tid == 0) {
          unsigned long long r0 = 0, r1 = 0, r2 = 0, r3 = 0;
          int lnk = nk;
          for (int i = 0; i < cl && lnk < 300; i++) {
            const unsigned long long rw = (i < 64) ? r0 : (i < 128) ? r1 : (i < 192) ? r2 : r3;
            if (sup[i] || ((rw >> (i & 63)) & 1ull)) continue;
            const float b1 = cx1[i], b2 = cy1[i], b3 = cx2[i], b4 = cy2[i];
            kx1[lnk] = b1; ky1[lnk] = b2; kx2[lnk] = b3; ky2[lnk] = b4; kar[lnk] = car[i];
            out[lnk] = cs[sidx[cpos + i]];
            out[300 + lnk] = 0.0f;
            out[600 + 4 * lnk + 0] = b1;
            out[600 + 4 * lnk + 1] = b2;
            out[600 + 4 * lnk + 2] = b3;
            out[600 + 4 * lnk + 3] = b4;
            lnk++;
            r0 |= msk[i * 4 + 0]; r1 |= msk[i * 4 + 1];
            r2 |= msk[i * 4 + 2]; r3 |= msk[i * 4 + 3];
          }
          sh_i[5] = lnk;
        }
        __syncthreads();
        nk = sh_i[5];
        cpos += cl;
        __syncthreads();
      }
    }
    processed = base + bn;
    hi64 = lo64;
  }
  __syncthreads();
  for (int r = nk + tid; r < 300; r += 1024) {
    out[r] = 0.f;
    out[300 + r] = -1.f;
    out[600 + 4 * r + 0] = 0.f;
    out[600 + 4 * r + 1] = 0.f;
    out[600 + 4 * r + 2] = 0.f;
    out[600 + 4 * r + 3] = 0.f;
  }
}

// ---------------- host ----------------
extern "C" void kernel_launch(void* const* d_in, const int* in_sizes, int n_in,
                              void* d_out, int out_size, void* d_ws, size_t ws_size,
                              hipStream_t stream) {
  (void)in_sizes; (void)n_in; (void)out_size; (void)ws_size;
  const float* feats[5];
  for (int ll = 0; ll < 5; ll++) feats[ll] = (const float*)d_in[1 + ll];
  const float* cls_w = (const float*)d_in[6];
  const float* cls_b = (const float*)d_in[7];
  const float* cls_ow = (const float*)d_in[8];
  const float* cls_ob = (const float*)d_in[9];
  const float* reg_w = (const float*)d_in[10];
  const float* reg_b = (const float*)d_in[11];
  const float* reg_ow = (const float*)d_in[12];
  const float* reg_ob = (const float*)d_in[13];

  static const int AOFF[5] = {0, 1638400, 2048000, 2150400, 2176000}; // 256*cumHW
  const size_t ACT = 2182400;  // fp32 activations per head
  const size_t PLH = 2182400;  // f16 elements per plane

  float* wsf = (float*)d_ws;
  float* ACC0 = wsf;                       // reg K-half 0 (final reg acts in place)
  float* ACC1 = wsf + ACT;                 // reg K-half 1
  float* clsA = wsf + 2 * ACT;             // cls fp32 ping
  float* clsB = wsf + 3 * ACT;             // cls fp32 pong
  f16* slotA = (f16*)(wsf + 4 * ACT);      // reg hi/lo planes
  f16* slotB = (f16*)(wsf + 5 * ACT);      // reg hi/lo planes (also feat pack)
  float* wt = wsf + 6 * ACT;               // cls re-laid weights: 4*2304*64 = 589824
  f16* wpkh = (f16*)(wsf + 6 * ACT + 589824);   // reg hi weights
  f16* wpkl = (f16*)(wsf + 6 * ACT + 884736);   // reg lo weights
  unsigned short* zbuf = (unsigned short*)(wsf + 6 * ACT + 1179648);  // 16 floats
  float* scores = wsf + 6 * ACT + 1179664;
  float* regs = scores + 76736;
  float* cand_s = regs + 306912;
  float* cand_b = cand_s + 76736;
  int* cand_n = (int*)(cand_b + 306944);
  int* meta = cand_n + 76736;
  float* wt2o = (float*)(meta + 1032);

  FcvArgs fa;
  for (int ll = 0; ll < 5; ll++) fa.f[ll] = feats[ll];
  fa.hi = slotB;
  fa.lo = slotB + PLH;
  fa.zbuf = zbuf;
  featcvt_k<<<dim3(135, 8), dim3(256), 0, stream>>>(fa);
  wtro_k<<<dim3(9), dim3(256), 0, stream>>>(cls_ow, reg_ow, wt2o);

  float* clsBufs[2] = {clsA, clsB};
  for (int layer = 0; layer < 4; layer++) {
    wsplit_k<<<dim3(2304), dim3(256), 0, stream>>>(reg_w + (size_t)layer * 589824, wpkh, wpkl);
    WtrArgs wa;
    wa.src[0] = cls_w + (size_t)layer * 589824;
    wa.src[1] = wa.src[0];
    wa.dst = wt;
    wtr_k<<<dim3(32, 4, 1), dim3(256), 0, stream>>>(wa);

    FusedArgs fu;
    if (layer == 0) {
      fu.in_hi = slotB;
      fu.in_lo = slotB + PLH;
    } else {
      f16* s = (layer & 1) ? slotA : slotB;
      fu.in_hi = s;
      fu.in_lo = s + PLH;
    }
    fu.w_hi = wpkh;
    fu.w_lo = wpkl;
    fu.acc0 = ACC0;
    fu.acc1 = ACC1;
    fu.zbuf = (const f16*)zbuf;
    fu.cw = wt;
    fu.cb = cls_b + layer * 256;
    for (int ll = 0; ll < 5; ll++) {
      fu.cout[ll] = clsBufs[layer & 1] + AOFF[ll];
      fu.cin[ll] = (layer == 0) ? feats[ll]
                                : (const float*)(clsBufs[(layer - 1) & 1] + AOFF[ll]);
    }
    fused_trunk<<<dim3(592), dim3(256), 0, stream>>>(fu);

    EpiArgs ea;
    f16* outS = (layer & 1) ? slotB : slotA;  // L0->A, L1->B, L2->A, L3 in-place fp32
    ea.a0 = ACC0;
    ea.a1 = ACC1;
    ea.bias = reg_b + layer * 256;
    ea.hi = outS;
    ea.lo = outS + PLH;
    ea.last = (layer == 3) ? 1 : 0;
    epi_k<<<dim3(135, 8), dim3(256), 0, stream>>>(ea);
  }

  Out2Args oa;
  for (int ll = 0; ll < 5; ll++) {
    oa.in[0][ll] = clsB + AOFF[ll];
    oa.in[1][ll] = ACC0 + AOFF[ll];
  }
  oa.w = wt2o;
  oa.b[0] = cls_ob;
  oa.b[1] = reg_ob;
  oa.dst[0] = scores;
  oa.dst[1] = regs;
  conv_out2<<<dim3(139, 5), dim3(192), 0, stream>>>(oa);

  init_k<<<dim3(5), dim3(256), 0, stream>>>(meta);
  decode_k<<<dim3((N_ANCH + 255) / 256), dim3(256), 0, stream>>>(scores, regs, cand_s,
                                                                 (float4*)cand_b, cand_n, meta);
  nms2_k<<<dim3(1), dim3(1024), 0, stream>>>(cand_s, (const float4*)cand_b, cand_n, meta,
                                             (float*)d_out);
}

// Round 6
// 1371.605 us; speedup vs baseline: 1.2589x; 1.0364x over previous
//
#include <hip/hip_runtime.h>
#include <math.h>

#define N_ANCH 76725
#define SORT_N 4096
#define NBKT 1024
#define BBASE 0x3D40u

typedef _Float16 f16;
typedef _Float16 f16x8 __attribute__((ext_vector_type(8)));
typedef float f32x4 __attribute__((ext_vector_type(4)));

__device__ __forceinline__ int pick5(int l, int a, int b, int c, int d, int e) {
  int r = a;
  if (l == 1) r = b;
  if (l == 2) r = c;
  if (l == 3) r = d;
  if (l == 4) r = e;
  return r;
}

// 64-position tiling (8x8): 139 tiles (conv_out2)
__device__ __forceinline__ void tile_to_level(int tile, int& lvl, int& t) {
  int l = 0;
  if (tile >= 100) l = 1;
  if (tile >= 125) l = 2;
  if (tile >= 134) l = 3;
  if (tile >= 138) l = 4;
  lvl = l;
  t = tile - pick5(l, 0, 100, 125, 134, 138);
}

// 64-linear-position tiling: 135 tiles (featcvt / epi)
__device__ __forceinline__ int tile64_lvl(int bx, int& t) {
  int l = 0;
  if (bx >= 100) l = 1;
  if (bx >= 125) l = 2;
  if (bx >= 132) l = 3;
  if (bx >= 134) l = 4;
  t = bx - pick5(l, 0, 100, 125, 132, 134);
  return l;
}

// fp32 -> f16 hi + (scaled by 2^12) f16 lo.  hi forced away from f16-denormal range.
__device__ __forceinline__ void split16(float v, f16& h, f16& l) {
  f16 hh = (f16)v;
  if (fabsf(v) < 6.103515625e-5f) hh = (f16)0.f;
  h = hh;
  l = (f16)((v - (float)hh) * 4096.f);
}

// async global->LDS, 16B per lane; dst wave-uniform base, lane i lands at dst+16*i
__device__ __forceinline__ void glds16h(const void* g, void* l) {
  __builtin_amdgcn_global_load_lds(
      (const __attribute__((address_space(1))) unsigned int*)g,
      (__attribute__((address_space(3))) unsigned int*)l, 16, 0, 0);
}

__device__ __forceinline__ void glds16(const float* g, float* l) {
  __builtin_amdgcn_global_load_lds(
      (const __attribute__((address_space(1))) unsigned int*)g,
      (__attribute__((address_space(3))) unsigned int*)l, 16, 0, 0);
}

// ---------------- feats fp32 NCHW -> packed [pos][ci] hi/lo f16 planes (reg path) ----------------
struct FcvArgs {
  const float* f[5];
  f16* hi;
  f16* lo;
  unsigned short* zbuf;
};

__global__ __launch_bounds__(256) void featcvt_k(FcvArgs a) {
  __shared__ float tile[32][65];
  int t;
  const int l = tile64_lvl(blockIdx.x, t);
  const int W = 80 >> l, HW = W * W;
  const int p0 = t * 64;
  const int apos = pick5(l, 0, 6400, 8000, 8400, 8500);
  const int ci0 = blockIdx.y * 32;
  const int tid = threadIdx.x;
  if (blockIdx.x == 0 && blockIdx.y == 0 && tid < 32) a.zbuf[tid] = 0;
  const float* __restrict__ src = a.f[l];
  #pragma unroll
  for (int i = 0; i < 8; i++) {
    const int j = tid + 256 * i;
    const int ci = j >> 6, p = j & 63;
    float v = 0.f;
    if (p0 + p < HW) v = src[(ci0 + ci) * HW + p0 + p];
    tile[ci][p] = v;
  }
  __syncthreads();
  const int p_l = tid >> 2, cq = tid & 3;
  if (p0 + p_l < HW) {
    union { f16 h[8]; uint4 v; } uh, ul;
    #pragma unroll
    for (int u = 0; u < 8; u++) split16(tile[cq * 8 + u][p_l], uh.h[u], ul.h[u]);
    const size_t base = (size_t)(apos + p0 + p_l) * 256 + ci0 + cq * 8;
    *(uint4*)(a.hi + base) = uh.v;
    *(uint4*)(a.lo + base) = ul.v;
  }
}

// ---------------- reg trunk weights (all 4 layers) -> hi/lo f16, [layer][c][co 256][k 32] ----------------
__global__ __launch_bounds__(256) void wsplit_k(const float* __restrict__ reg_w,
                                                f16* __restrict__ whi,
                                                f16* __restrict__ wlo) {
  const int e = blockIdx.x * 256 + threadIdx.x;  // 0..589823
  const int layer = blockIdx.y;
  const float* src = reg_w + (size_t)layer * 589824;
  const int k = e & 31, co = (e >> 5) & 255, c = e >> 13;
  const int tap = c >> 3, ciq = c & 7;
  const int ci = ciq * 32 + k;
  const float v = src[((size_t)co * 256 + ci) * 9 + tap];
  f16 h, lo;
  split16(v, h, lo);
  whi[(size_t)layer * 589824 + e] = h;
  wlo[(size_t)layer * 589824 + e] = lo;
}

// ---------------- cls weight re-layout (all 4 layers): [layer][cog64][2304][64] ----------------
struct WtrArgs {
  const float* src;     // cls_w, 4 layers
  float* dst;
};

__global__ __launch_bounds__(256) void wtr_k(WtrArgs a) {
  __shared__ float tile[72][65];
  const int r0 = blockIdx.x * 72;   // 32 groups
  const int cog = blockIdx.y;       // 4 groups of 64 co
  const int co0 = cog * 64;
  const int layer = blockIdx.z;
  const float* __restrict__ src = a.src + (size_t)layer * 589824;
  float* __restrict__ dst = a.dst + (size_t)layer * 589824 + ((size_t)cog * 2304 + r0) * 64;
  const int tid = threadIdx.x;
  #pragma unroll
  for (int i = 0; i < 18; i++) {
    int e = tid + 256 * i;  // < 4608
    int co = e / 72;
    int r = e - co * 72;
    tile[r][co] = src[(size_t)(co0 + co) * 2304 + r0 + r];
  }
  __syncthreads();
  #pragma unroll
  for (int i = 0; i < 18; i++) {
    int e = tid + 256 * i;
    int r = e >> 6;
    int co = e & 63;
    dst[(size_t)r * 64 + co] = tile[r][co];
  }
}

// ---------------- helpers for fp32 conv body (bit-exact baseline math) ----------------
__device__ __forceinline__ void a_load(const float* __restrict__ in, int ci0,
                                       int ty0, int tx0, int W, int HW, int tid,
                                       float a_reg[6]) {
  const float* inc = in + ci0 * HW;
  #pragma unroll
  for (int i = 0; i < 6; i++) {
    int e = tid + 256 * i;
    float v = 0.f;
    if (e < 1440) {
      int ci = e / 180;
      int rem = e - ci * 180;
      int yy = rem / 10;
      int xx = rem - yy * 10;
      int gy = ty0 + yy - 1, gx = tx0 + xx - 1;
      if ((unsigned)gy < (unsigned)W && (unsigned)gx < (unsigned)W)
        v = inc[ci * HW + gy * W + gx];
    }
    a_reg[i] = v;
  }
}

__device__ __forceinline__ void a_store(int tid, const float a_reg[6],
                                        float As[8][18][12]) {
  #pragma unroll
  for (int i = 0; i < 6; i++) {
    int e = tid + 256 * i;
    if (e < 1440) {
      int ci = e / 180;
      int rem = e - ci * 180;
      int yy = rem / 10;
      int xx = rem - yy * 10;
      As[ci][yy][xx] = a_reg[i];
    }
  }
}

// ---------------- FUSED per-layer trunk: bx%3==0 -> reg MFMA (296), else cls fp32 (592) ----------------
struct FusedArgs {
  const f16* in_hi;
  const f16* in_lo;
  const f16* w_hi;
  const f16* w_lo;
  float* acc0;          // reg K-half 0
  float* acc1;          // reg K-half 1
  const f16* zbuf;
  const float* cin[5];  // cls inputs per level
  float* cout[5];       // cls outputs per level
  const float* cw;      // re-laid cls weights [cog64][2304][64]
  const float* cb;      // cls bias
};

__global__ __launch_bounds__(256, 2) void fused_trunk(FusedArgs a) {
  __shared__ __align__(16) char smem[65536];
  const int bx = blockIdx.x;
  const int tid = threadIdx.x;
  const int q3 = bx / 3, r3 = bx - q3 * 3;
  if (r3 == 0) {
    // ===== reg head: MFMA split-f16 implicit GEMM, 128co x 128pos, K-split-2 =====
    f16 (*Xh)[4096] = (f16 (*)[4096])(smem);
    f16 (*Xl)[4096] = (f16 (*)[4096])(smem + 16384);
    f16 (*Wh)[4096] = (f16 (*)[4096])(smem + 32768);
    f16 (*Wl)[4096] = (f16 (*)[4096])(smem + 49152);
    const int rb = q3;               // 0..295
    const int combo = rb & 3, tl = rb >> 2;
    const int cog = combo >> 1, kh = combo & 1;
    int l = 0;
    if (tl >= 50) l = 1;
    if (tl >= 65) l = 2;
    if (tl >= 71) l = 3;
    if (tl >= 73) l = 4;
    const int t = tl - pick5(l, 0, 50, 65, 71, 73);
    const int W = 80 >> l, HW = W * W, tX = (W + 7) >> 3;
    const int ty0 = (t / tX) * 16, tx0 = (t % tX) * 8;
    const int apos = pick5(l, 0, 6400, 8000, 8400, 8500);
    const int co0 = cog * 128;
    const int lane = tid & 63, wv = tid >> 6;
    const int ln15 = lane & 15, lh = lane >> 4;
    const int wco = wv & 1, wpos = wv >> 1;
    const f16* __restrict__ ihi = a.in_hi;
    const f16* __restrict__ ilo = a.in_lo;
    const f16* __restrict__ whi = a.w_hi;
    const f16* __restrict__ wlo = a.w_lo;

    f32x4 accA[4][4] = {};
    f32x4 accB[4][4] = {};

    auto stage = [&](int c, int buf) {
      const int tap = c >> 3, ciq = c & 7;
      const int dy = tap / 3 - 1, dx = tap - (tap / 3) * 3 - 1;
      #pragma unroll
      for (int i = 0; i < 2; i++) {
        const int s = (wv * 2 + i) * 64 + lane;
        const int pos = s >> 2, kq = s & 3;
        const int kqd = kq ^ (pos & 3);
        const int gy = ty0 + (pos >> 3) + dy, gx = tx0 + (pos & 7) + dx;
        const bool v = (unsigned)gy < (unsigned)W && (unsigned)gx < (unsigned)W;
        const int off = (apos + gy * W + gx) * 256 + ciq * 32 + kqd * 8;
        glds16h(v ? (const void*)(ihi + off) : (const void*)a.zbuf, &Xh[buf][(wv * 2 + i) * 512]);
        glds16h(v ? (const void*)(ilo + off) : (const void*)a.zbuf, &Xl[buf][(wv * 2 + i) * 512]);
      }
      const f16* wh = whi + (size_t)c * 8192;
      const f16* wl = wlo + (size_t)c * 8192;
      #pragma unroll
      for (int i = 0; i < 2; i++) {
        const int s = (wv * 2 + i) * 64 + lane;
        const int col = s >> 2, kq = s & 3;
        const int kqd = kq ^ (col & 3);
        const int off = (co0 + col) * 32 + kqd * 8;
        glds16h(wh + off, &Wh[buf][(wv * 2 + i) * 512]);
        glds16h(wl + off, &Wl[buf][(wv * 2 + i) * 512]);
      }
    };

    const int c0 = kh * 36;
    stage(c0, 0);
    __syncthreads();
    for (int j = 0; j < 36; j++) {
      const int b = j & 1;
      if (j < 35) stage(c0 + j + 1, b ^ 1);
      const int slot = (lh ^ (ln15 & 3)) * 8;
      const int aro = (wco * 64 + ln15) * 32 + slot;
      const int bro = (wpos * 64 + ln15) * 32 + slot;
      f16x8 ah[4], al[4];
      #pragma unroll
      for (int mi = 0; mi < 4; mi++) {
        ah[mi] = *(const f16x8*)&Wh[b][aro + mi * 512];
        al[mi] = *(const f16x8*)&Wl[b][aro + mi * 512];
      }
      #pragma unroll
      for (int ni = 0; ni < 4; ni++) {
        const f16x8 bhv = *(const f16x8*)&Xh[b][bro + ni * 512];
        const f16x8 blv = *(const f16x8*)&Xl[b][bro + ni * 512];
        #pragma unroll
        for (int mi = 0; mi < 4; mi++) {
          accA[mi][ni] = __builtin_amdgcn_mfma_f32_16x16x32_f16(ah[mi], bhv, accA[mi][ni], 0, 0, 0);
          accB[mi][ni] = __builtin_amdgcn_mfma_f32_16x16x32_f16(ah[mi], blv, accB[mi][ni], 0, 0, 0);
          accB[mi][ni] = __builtin_amdgcn_mfma_f32_16x16x32_f16(al[mi], bhv, accB[mi][ni], 0, 0, 0);
        }
      }
      __syncthreads();
    }

    const int aoffF = pick5(l, 0, 1638400, 2048000, 2150400, 2176000);
    float* __restrict__ dst = (kh == 0 ? a.acc0 : a.acc1) + aoffF;
    #pragma unroll
    for (int ni = 0; ni < 4; ni++) {
      const int pos = wpos * 64 + ni * 16 + ln15;
      const int gy = ty0 + (pos >> 3), gx = tx0 + (pos & 7);
      if (gy < W && gx < W) {
        #pragma unroll
        for (int mi = 0; mi < 4; mi++) {
          const int co = co0 + wco * 64 + mi * 16 + lh * 4;
          float* d = dst + (size_t)co * HW + gy * W + gx;
          #pragma unroll
          for (int r = 0; r < 4; r++)
            d[(size_t)r * HW] = accA[mi][ni][r] + accB[mi][ni][r] * 2.44140625e-4f;
        }
      }
    }
  } else {
    // ===== cls head: baseline fp32 vector conv, 32-co blocks (bit-exact chains) =====
    float (*As)[8][18][12] = (float (*)[8][18][12])(smem);         // [2][8][18][12] = 13824 B
    float (*Ws)[72][32] = (float (*)[72][32])(smem + 13824);       // [2][72][32] = 18432 B
    const int cls_idx = q3 * 2 + (r3 - 1);   // 0..591
    const int cog = cls_idx & 7;             // 8 groups of 32 co
    const int tl = cls_idx >> 3;             // 0..73
    int l = 0;
    if (tl >= 50) l = 1;
    if (tl >= 65) l = 2;
    if (tl >= 71) l = 3;
    if (tl >= 73) l = 4;
    const int lvl = l;
    const int t = tl - pick5(l, 0, 50, 65, 71, 73);
    const int W = 80 >> lvl;
    const int HW = W * W;
    const int tX = (W + 7) >> 3;
    const int ty0 = (t / tX) * 16, tx0 = (t % tX) * 8;
    const int co0 = cog << 5;
    const int cog64 = cog >> 1, half = cog & 1;
    const float* __restrict__ in = a.cin[lvl];
    float* __restrict__ out = a.cout[lvl];
    const float* __restrict__ wsrc = a.cw + (size_t)cog64 * 2304 * 64;
    const int lane = tid & 63, wv = tid >> 6;
    const int cop = tid & 7;
    const int ry = tid >> 4;          // 0..15
    const int xh = (tid >> 3) & 1;    // x-half
    float acc[4][4] = {};
    float a_reg[6];

    // stage 72 rows x 32 co per k-chunk; per-lane strided source gather, linear LDS dst
    auto stage32 = [&](const float* wchunk, float* wbuf) {
      #pragma unroll
      for (int i2 = 0; i2 < 3; i2++) {
        int j = wv + 4 * i2;          // wave-uniform
        if (j < 9) {
          const float* src = wchunk + (j * 8 + (lane >> 3)) * 64 + half * 32 + (lane & 7) * 4;
          glds16(src, wbuf + j * 256);
        }
      }
    };

    stage32(wsrc, &Ws[0][0][0]);
    a_load(in, 0, ty0, tx0, W, HW, tid, a_reg);
    a_store(tid, a_reg, As[0]);
    __syncthreads();

    for (int k = 0; k < 32; k++) {
      const int kb = k & 1;
      const bool more = k < 31;
      if (more) {
        stage32(wsrc + (size_t)(k + 1) * 4608, &Ws[kb ^ 1][0][0]);
        a_load(in, (k + 1) * 8, ty0, tx0, W, HW, tid, a_reg);
      }
      #pragma unroll 2
      for (int ci = 0; ci < 8; ci++) {
        #pragma unroll
        for (int ty = 0; ty < 3; ty++) {
          const float* ar = &As[kb][ci][ry + ty][xh * 4];
          float4 a0 = *(const float4*)ar;
          float2 a1 = *(const float2*)(ar + 4);
          float av[6] = {a0.x, a0.y, a0.z, a0.w, a1.x, a1.y};
          #pragma unroll
          for (int tx = 0; tx < 3; tx++) {
            float4 w4 = *(const float4*)&Ws[kb][ci * 9 + ty * 3 + tx][cop * 4];
            #pragma unroll
            for (int p = 0; p < 4; p++) {
              acc[p][0] = fmaf(av[tx + p], w4.x, acc[p][0]);
              acc[p][1] = fmaf(av[tx + p], w4.y, acc[p][1]);
              acc[p][2] = fmaf(av[tx + p], w4.z, acc[p][2]);
              acc[p][3] = fmaf(av[tx + p], w4.w, acc[p][3]);
            }
          }
        }
      }
      if (more) {
        a_store(tid, a_reg, As[kb ^ 1]);
        __syncthreads();
      }
    }
    const float4 bias = *(const float4*)&a.cb[co0 + cop * 4];
    const int oy = ty0 + ry;
    if (oy < W) {
      #pragma unroll
      for (int p = 0; p < 4; p++) {
        int ox = tx0 + xh * 4 + p;
        if (ox < W) {
          int base = oy * W + ox;
          out[(co0 + cop * 4 + 0) * HW + base] = fmaxf(acc[p][0] + bias.x, 0.f);
          out[(co0 + cop * 4 + 1) * HW + base] = fmaxf(acc[p][1] + bias.y, 0.f);
          out[(co0 + cop * 4 + 2) * HW + base] = fmaxf(acc[p][2] + bias.z, 0.f);
          out[(co0 + cop * 4 + 3) * HW + base] = fmaxf(acc[p][3] + bias.w, 0.f);
        }
      }
    }
  }
}

// ---------------- reg per-layer epilogue: sum K-halves, bias+relu, re-split ----------------
struct EpiArgs {
  float* a0;            // K-half 0 (also in-place fp32 dst for last layer)
  const float* a1;      // K-half 1
  const float* bias;
  f16* hi;
  f16* lo;
  int last;
};

__global__ __launch_bounds__(256) void epi_k(EpiArgs a) {
  __shared__ float tile[32][65];
  int t;
  const int l = tile64_lvl(blockIdx.x, t);
  const int W = 80 >> l, HW = W * W;
  const int p0 = t * 64;
  const int apos = pick5(l, 0, 6400, 8000, 8400, 8500);
  const int ci0 = blockIdx.y * 32;
  const int tid = threadIdx.x;
  float* __restrict__ s0 = a.a0 + (size_t)apos * 256;
  const float* __restrict__ s1 = a.a1 + (size_t)apos * 256;
  const float* __restrict__ bias = a.bias;
  #pragma unroll
  for (int i = 0; i < 8; i++) {
    const int j = tid + 256 * i;
    const int ci = j >> 6, p = j & 63;
    float v = 0.f;
    if (p0 + p < HW) {
      const size_t off = (size_t)(ci0 + ci) * HW + p0 + p;
      float x = s0[off];
      float y = s1[off];
      v = x + y;
    }
    tile[ci][p] = fmaxf(v + bias[ci0 + ci], 0.f);
  }
  __syncthreads();
  if (a.last) {
    #pragma unroll
    for (int i = 0; i < 8; i++) {
      const int j = tid + 256 * i;
      const int ci = j >> 6, p = j & 63;
      if (p0 + p < HW) s0[(size_t)(ci0 + ci) * HW + p0 + p] = tile[ci][p];
    }
  } else {
    const int p_l = tid >> 2, cq = tid & 3;
    if (p0 + p_l < HW) {
      union { f16 h[8]; uint4 v; } uh, ul;
      #pragma unroll
      for (int u = 0; u < 8; u++) split16(tile[cq * 8 + u][p_l], uh.h[u], ul.h[u]);
      const size_t base = (size_t)(apos + p0 + p_l) * 256 + ci0 + cq * 8;
      *(uint4*)(a.hi + base) = uh.v;
      *(uint4*)(a.lo + base) = ul.v;
    }
  }
}

// ---------------- output-conv weight transpose ----------------
struct Out2Args {
  const float* in[2][5];
  const float* w;
  const float* b[2];
  float* dst[2];
};

__global__ __launch_bounds__(256) void wtro_k(const float* __restrict__ cls_ow,
                                              const float* __restrict__ reg_ow,
                                              float* __restrict__ dst) {
  int r = blockIdx.x * 256 + threadIdx.x;   // 0..2303
  if (r >= 2304) return;
  for (int g = 0; g < 5; g++) {
    #pragma unroll
    for (int s = 0; s < 16; s++) {
      int w = s >> 2, c = s & 3;
      float v = 0.f;
      if (w < 3 && c < 3) {
        int cl = 3 * w + c;
        v = (g == 0) ? cls_ow[(size_t)cl * 2304 + r]
                     : reg_ow[(size_t)((g - 1) * 9 + cl) * 2304 + r];
      }
      dst[((size_t)g * 2304 + r) * 16 + s] = v;
    }
  }
}

// ---------------- fused output convs (unchanged) ----------------
__device__ __forceinline__ void ao_load(const float* __restrict__ in, int ci0,
                                        int ty0, int tx0, int W, int HW, int tid,
                                        float a_reg[5]) {
  const float* inc = in + ci0 * HW;
  #pragma unroll
  for (int i = 0; i < 5; i++) {
    int e = tid + 192 * i;
    float v = 0.f;
    if (e < 800) {
      int ci = e / 100;
      int rem = e - ci * 100;
      int yy = rem / 10;
      int xx = rem - yy * 10;
      int gy = ty0 + yy - 1, gx = tx0 + xx - 1;
      if ((unsigned)gy < (unsigned)W && (unsigned)gx < (unsigned)W)
        v = inc[ci * HW + gy * W + gx];
    }
    a_reg[i] = v;
  }
}

__device__ __forceinline__ void ao_store(int tid, const float a_reg[5],
                                         float As[8][10][12]) {
  #pragma unroll
  for (int i = 0; i < 5; i++) {
    int e = tid + 192 * i;
    if (e < 800) {
      int ci = e / 100;
      int rem = e - ci * 100;
      int yy = rem / 10;
      int xx = rem - yy * 10;
      As[ci][yy][xx] = a_reg[i];
    }
  }
}

__global__ __launch_bounds__(192) void conv_out2(Out2Args args) {
  __shared__ float As[2][8][10][12];
  __shared__ __align__(16) float Wg[2][8][9][16];
  int lvl, t;
  tile_to_level(blockIdx.x, lvl, t);
  const int g = blockIdx.y;
  const int head = (g == 0) ? 0 : 1;
  const int co0 = (g == 0) ? 0 : (g - 1) * 9;
  const int W = 80 >> lvl;
  const int HW = W * W;
  const int tX = (W + 7) >> 3;
  const int ty0 = (t / tX) * 8, tx0 = (t % tX) * 8;
  const float* __restrict__ in = args.in[head][lvl];
  const float* __restrict__ wg = args.w + (size_t)g * 2304 * 16;
  const int tid = threadIdx.x;
  const int wv = tid >> 6;
  const int lane = tid & 63;
  const int y = lane >> 3, x = lane & 7;
  float acc0 = 0.f, acc1 = 0.f, acc2 = 0.f;
  float a_reg[5];
  float4 w_reg[2];

  ao_load(in, 0, ty0, tx0, W, HW, tid, a_reg);
  {
    const float4* wsrc4 = (const float4*)wg;
    #pragma unroll
    for (int i = 0; i < 2; i++) {
      int e = tid + 192 * i;
      if (e < 288) w_reg[i] = wsrc4[e];
    }
  }
  ao_store(tid, a_reg, As[0]);
  {
    float4* wdst4 = (float4*)&Wg[0][0][0][0];
    #pragma unroll
    for (int i = 0; i < 2; i++) {
      int e = tid + 192 * i;
      if (e < 288) wdst4[e] = w_reg[i];
    }
  }
  __syncthreads();

  for (int k = 0; k < 32; k++) {
    const int kb = k & 1;
    const bool more = k < 31;
    if (more) {
      ao_load(in, (k + 1) * 8, ty0, tx0, W, HW, tid, a_reg);
      const float4* wsrc4 = (const float4*)(wg + (size_t)(k + 1) * 1152);
      #pragma unroll
      for (int i = 0; i < 2; i++) {
        int e = tid + 192 * i;
        if (e < 288) w_reg[i] = wsrc4[e];
      }
    }
    #pragma unroll 2
    for (int ci = 0; ci < 8; ci++) {
      #pragma unroll
      for (int ty = 0; ty < 3; ty++) {
        float a0 = As[kb][ci][y + ty][x + 0];
        float a1 = As[kb][ci][y + ty][x + 1];
        float a2 = As[kb][ci][y + ty][x + 2];
        #pragma unroll
        for (int tx = 0; tx < 3; tx++) {
          float av = (tx == 0) ? a0 : (tx == 1) ? a1 : a2;
          float4 w4 = *(const float4*)&Wg[kb][ci][ty * 3 + tx][4 * wv];
          acc0 = fmaf(av, w4.x, acc0);
          acc1 = fmaf(av, w4.y, acc1);
          acc2 = fmaf(av, w4.z, acc2);
        }
      }
    }
    if (more) {
      ao_store(tid, a_reg, As[kb ^ 1]);
      float4* wdst4 = (float4*)&Wg[kb ^ 1][0][0][0];
      #pragma unroll
      for (int i = 0; i < 2; i++) {
        int e = tid + 192 * i;
        if (e < 288) wdst4[e] = w_reg[i];
      }
      __syncthreads();
    }
  }
  const int oy = ty0 + y, ox = tx0 + x;
  if (oy < W && ox < W) {
    const int cell = oy * W + ox;
    const int aoff = pick5(lvl, 0, 57600, 72000, 75600, 76500);
    float* dst = args.dst[head];
    const float* bias = args.b[head];
    #pragma unroll
    for (int c = 0; c < 3; c++) {
      int co = co0 + 3 * wv + c;
      float v = ((c == 0) ? acc0 : (c == 1) ? acc1 : acc2) + bias[co];
      if (head == 0) {
        v = 1.f / (1.f + expf(-v));
        dst[aoff + cell * 9 + co] = v;
      } else {
        dst[(size_t)aoff * 4 + cell * 36 + co] = v;
      }
    }
  }
}

// ---------------- init / decode (unchanged) ----------------
__global__ void init_k(int* meta) {
  int i = blockIdx.x * 256 + threadIdx.x;
  if (i < 1 + NBKT) meta[i] = 0;
}

__global__ __launch_bounds__(256) void decode_k(const float* __restrict__ scores,
                                                const float* __restrict__ regs,
                                                float* cand_s, float4* cand_b,
                                                int* cand_n, int* meta) {
  int n = blockIdx.x * 256 + threadIdx.x;
  if (n >= N_ANCH) return;
  int lvl = 0;
  if (n >= 57600) lvl = 1;
  if (n >= 72000) lvl = 2;
  if (n >= 75600) lvl = 3;
  if (n >= 76500) lvl = 4;
  const int aoff = pick5(lvl, 0, 57600, 72000, 75600, 76500);
  const int W = 80 >> lvl;
  int r = n - aoff;
  int a = r % 9;
  int cell = r / 9;
  int x = cell % W, y = cell / W;
  double stride = (double)(8 << lvl);
  double base = (double)(32 << lvl);
  int si = a % 3, ri = a / 3;
  double s = (si == 0) ? 1.0 : (si == 1) ? 1.2599210498948731648 : 1.5874010519681994748;
  double ratio = (ri == 0) ? 0.5 : (ri == 1) ? 1.0 : 2.0;
  double ws0 = base * s;
  double area = ws0 * ws0;
  double w = sqrt(area / ratio);
  double h = w * ratio;
  double cx = ((double)x + 0.5) * stride;
  double cy = ((double)y + 0.5) * stride;
  float ax1 = (float)(cx - 0.5 * w);
  float ay1 = (float)(cy - 0.5 * h);
  float ax2 = (float)(cx + (w - 0.5 * w));
  float ay2 = (float)(cy + (h - 0.5 * h));
  float4 rg = ((const float4*)regs)[n];
  float aw = ax2 - ax1, ah = ay2 - ay1;
  float acx = ax1 + 0.5f * aw, acy = ay1 + 0.5f * ah;
  float pcx = acx + rg.x * 0.1f * aw;
  float pcy = acy + rg.y * 0.1f * ah;
  float pw = expf(rg.z * 0.2f) * aw;
  float ph = expf(rg.w * 0.2f) * ah;
  float x1 = pcx - 0.5f * pw, y1 = pcy - 0.5f * ph;
  float x2 = pcx + 0.5f * pw, y2 = pcy + 0.5f * ph;
  x1 = fminf(fmaxf(x1, 0.f), 640.f);
  y1 = fminf(fmaxf(y1, 0.f), 640.f);
  x2 = fminf(fmaxf(x2, 0.f), 640.f);
  y2 = fminf(fmaxf(y2, 0.f), 640.f);
  float sc = scores[n];
  if (sc > 0.05f) {
    int p = atomicAdd(&meta[0], 1);
    cand_s[p] = sc;
    cand_b[p] = make_float4(x1, y1, x2, y2);
    cand_n[p] = n;
    unsigned int sb = __float_as_uint(sc);
    int bk = (int)(sb >> 16) - (int)BBASE;
    bk = max(0, min(NBKT - 1, bk));
    atomicAdd(&meta[1 + bk], 1);
  }
}

// ---------------- sort-based exact greedy NMS with chunked suppression masks ----------------
__global__ __launch_bounds__(1024) void nms2_k(const float* __restrict__ cs,
                                               const float4* __restrict__ cb,
                                               const int* __restrict__ cn,
                                               const int* __restrict__ meta,
                                               float* __restrict__ out) {
  __shared__ unsigned long long skey[SORT_N];   // reused as chunk scratch post-sort
  __shared__ int sidx[SORT_N];
  __shared__ int suf[NBKT];
  __shared__ float kx1[300], ky1[300], kx2[300], ky2[300], kar[300];
  __shared__ int sh_i[8];
  const int tid = threadIdx.x;
  const int m = min(meta[0], N_ANCH);

  for (int b = tid; b < NBKT; b += 1024) suf[b] = meta[1 + b];
  __syncthreads();
  for (int off = 1; off < NBKT; off <<= 1) {
    int v0 = suf[tid] + ((tid + off < NBKT) ? suf[tid + off] : 0);
    __syncthreads();
    suf[tid] = v0;
    __syncthreads();
  }

  int nk = 0;
  unsigned long long hi64 = ~0ULL;
  int processed = 0;

  while (nk < 300 && processed < m) {
    int base = 0;
    if (hi64 != ~0ULL) {
      if (tid == 0) sh_i[4] = 0;
      __syncthreads();
      int c = 0;
      for (int j = tid; j < m; j += 1024) {
        unsigned long long K = ((unsigned long long)__float_as_uint(cs[j]) << 32) |
                               (unsigned int)(~cn[j]);
        if (K >= hi64) c++;
      }
      atomicAdd(&sh_i[4], c);
      __syncthreads();
      base = sh_i[4];
      __syncthreads();
    }
    if (tid == 0) sh_i[3] = NBKT + 1;
    __syncthreads();
    {
      int T = tid;
      unsigned long long lo =
          (T == 0) ? 0ULL : ((unsigned long long)(((unsigned)T + BBASE) << 16) << 32);
      int c = suf[T] - base;
      if (lo < hi64 && c >= 1 && c <= SORT_N) atomicMin(&sh_i[3], T);
    }
    __syncthreads();
    int T = sh_i[3];
    __syncthreads();
    unsigned long long lo64;
    if (T <= NBKT) {
      lo64 = (T == 0) ? 0ULL : ((unsigned long long)(((unsigned)T + BBASE) << 16) << 32);
    } else {
      unsigned long long L = 0, H = hi64;
      while (H - L > 1) {
        unsigned long long mid = L + ((H - L) >> 1);
        if (tid == 0) sh_i[4] = 0;
        __syncthreads();
        int c = 0;
        for (int j = tid; j < m; j += 1024) {
          unsigned long long K = ((unsigned long long)__float_as_uint(cs[j]) << 32) |
                                 (unsigned int)(~cn[j]);
          if (K >= mid && K < hi64) c++;
        }
        atomicAdd(&sh_i[4], c);
        __syncthreads();
        int cc = sh_i[4];
        __syncthreads();
        if (cc > SORT_N) L = mid; else H = mid;
      }
      lo64 = H;
    }
    if (tid == 0) sh_i[0] = 0;
    __syncthreads();
    for (int j = tid; j < m; j += 1024) {
      unsigned long long K = ((unsigned long long)__float_as_uint(cs[j]) << 32) |
                             (unsigned int)(~cn[j]);
      if (K >= lo64 && K < hi64) {
        int p = atomicAdd(&sh_i[0], 1);
        if (p < SORT_N) { skey[p] = K; sidx[p] = j; }
      }
    }
    __syncthreads();
    int bn = min(sh_i[0], SORT_N);
    __syncthreads();
    for (int p = bn + tid; p < SORT_N; p += 1024) { skey[p] = 0; sidx[p] = 0; }
    __syncthreads();
    for (int k = 2; k <= SORT_N; k <<= 1) {
      for (int jj = k >> 1; jj > 0; jj >>= 1) {
        for (int i = tid; i < SORT_N; i += 1024) {
          int l2 = i ^ jj;
          if (l2 > i) {
            unsigned long long a = skey[i], b2 = skey[l2];
            bool desc = ((i & k) == 0);
            if ((a < b2) == desc) {
              skey[i] = b2; skey[l2] = a;
              int t2 = sidx[i]; sidx[i] = sidx[l2]; sidx[l2] = t2;
            }
          }
        }
        __syncthreads();
      }
    }
    // ---- chunked exact greedy: suppressed-by-kept flags + within-chunk masks ----
    {
      char* pool = (char*)skey;   // skey contents dead after sort (order lives in sidx)
      float* cx1 = (float*)pool;
      float* cy1 = cx1 + 256;
      float* cx2 = cy1 + 256;
      float* cy2 = cx2 + 256;
      float* car = cy2 + 256;
      int* sup = (int*)(car + 256);
      unsigned long long* msk = (unsigned long long*)(pool + 6144);  // [256][4]
      int cpos = 0;
      while (cpos < bn && nk < 300) {
        const int cl = min(256, bn - cpos);
        if (tid < 256) sup[tid] = 0;
        if (tid < cl) {
          float4 b = cb[sidx[cpos + tid]];
          cx1[tid] = b.x; cy1[tid] = b.y; cx2[tid] = b.z; cy2[tid] = b.w;
          car[tid] = (b.z - b.x) * (b.w - b.y);
        }
        __syncthreads();
        {
          const int i = tid >> 2, q = tid & 3;
          if (i < cl) {
            const float bx1 = cx1[i], by1 = cy1[i], bx2 = cx2[i], by2 = cy2[i], ba = car[i];
            int flag = 0;
            for (int k2 = q; k2 < nk; k2 += 4) {
              float xx1 = fmaxf(kx1[k2], bx1), yy1 = fmaxf(ky1[k2], by1);
              float xx2 = fminf(kx2[k2], bx2), yy2 = fminf(ky2[k2], by2);
              float inter = fmaxf(xx2 - xx1, 0.f) * fmaxf(yy2 - yy1, 0.f);
              if (inter / (ba + kar[k2] - inter + 1e-8f) > 0.5f) { flag = 1; break; }
            }
            if (flag) atomicOr(&sup[i], 1);
          }
        }
        {
          const int i = tid >> 2, w = tid & 3;
          unsigned long long bits = 0ull;
          if (i < cl) {
            const float ax1 = cx1[i], ay1 = cy1[i], ax2 = cx2[i], ay2 = cy2[i], aa = car[i];
            const int j0 = w * 64;
            for (int jj = 0; jj < 64; jj++) {
              const int j2 = j0 + jj;
              if (j2 > i && j2 < cl) {
                float xx1 = fmaxf(ax1, cx1[j2]), yy1 = fmaxf(ay1, cy1[j2]);
                float xx2 = fminf(ax2, cx2[j2]), yy2 = fminf(ay2, cy2[j2]);
                float inter = fmaxf(xx2 - xx1, 0.f) * fmaxf(yy2 - yy1, 0.f);
                if (inter / (car[j2] + aa - inter + 1e-8f) > 0.5f) bits |= (1ull << jj);
              }
            }
          }
          msk[(tid >> 2) * 4 + (tid & 3)] = bits;
        }
        __syncthreads();
        if (tid == 0) {
          unsigned long long r0 = 0, r1 = 0, r2 = 0, r3b = 0;
          int lnk = nk;
          for (int i = 0; i < cl && lnk < 300; i++) {
            const unsigned long long rw = (i < 64) ? r0 : (i < 128) ? r1 : (i < 192) ? r2 : r3b;
            if (sup[i] || ((rw >> (i & 63)) & 1ull)) continue;
            const float b1 = cx1[i], b2 = cy1[i], b3 = cx2[i], b4 = cy2[i];
            kx1[lnk] = b1; ky1[lnk] = b2; kx2[lnk] = b3; ky2[lnk] = b4; kar[lnk] = car[i];
            out[lnk] = cs[sidx[cpos + i]];
            out[300 + lnk] = 0.0f;
            out[600 + 4 * lnk + 0] = b1;
            out[600 + 4 * lnk + 1] = b2;
            out[600 + 4 * lnk + 2] = b3;
            out[600 + 4 * lnk + 3] = b4;
            lnk++;
            r0 |= msk[i * 4 + 0]; r1 |= msk[i * 4 + 1];
            r2 |= msk[i * 4 + 2]; r3b |= msk[i * 4 + 3];
          }
          sh_i[5] = lnk;
        }
        __syncthreads();
        nk = sh_i[5];
        cpos += cl;
        __syncthreads();
      }
    }
    processed = base + bn;
    hi64 = lo64;
  }
  __syncthreads();
  for (int r = nk + tid; r < 300; r += 1024) {
    out[r] = 0.f;
    out[300 + r] = -1.f;
    out[600 + 4 * r + 0] = 0.f;
    out[600 + 4 * r + 1] = 0.f;
    out[600 + 4 * r + 2] = 0.f;
    out[600 + 4 * r + 3] = 0.f;
  }
}

// ---------------- host ----------------
extern "C" void kernel_launch(void* const* d_in, const int* in_sizes, int n_in,
                              void* d_out, int out_size, void* d_ws, size_t ws_size,
                              hipStream_t stream) {
  (void)in_sizes; (void)n_in; (void)out_size; (void)ws_size;
  const float* feats[5];
  for (int ll = 0; ll < 5; ll++) feats[ll] = (const float*)d_in[1 + ll];
  const float* cls_w = (const float*)d_in[6];
  const float* cls_b = (const float*)d_in[7];
  const float* cls_ow = (const float*)d_in[8];
  const float* cls_ob = (const float*)d_in[9];
  const float* reg_w = (const float*)d_in[10];
  const float* reg_b = (const float*)d_in[11];
  const float* reg_ow = (const float*)d_in[12];
  const float* reg_ob = (const float*)d_in[13];

  static const int AOFF[5] = {0, 1638400, 2048000, 2150400, 2176000}; // 256*cumHW
  const size_t ACT = 2182400;  // fp32 activations per head
  const size_t PLH = 2182400;  // f16 elements per plane

  float* wsf = (float*)d_ws;
  float* ACC0 = wsf;                       // reg K-half 0 (final reg acts in place)
  float* ACC1 = wsf + ACT;                 // reg K-half 1
  float* clsA = wsf + 2 * ACT;             // cls fp32 ping
  float* clsB = wsf + 3 * ACT;             // cls fp32 pong
  f16* slotA = (f16*)(wsf + 4 * ACT);      // reg hi/lo planes
  f16* slotB = (f16*)(wsf + 5 * ACT);      // reg hi/lo planes (also feat pack)
  float* wt4 = wsf + 6 * ACT;                       // cls re-laid weights, 4 layers: 2359296 floats
  f16* wpkh4 = (f16*)(wsf + 6 * ACT + 2359296);     // reg hi weights, 4 layers (1179648 floats)
  f16* wpkl4 = (f16*)(wsf + 6 * ACT + 3538944);     // reg lo weights, 4 layers (1179648 floats)
  unsigned short* zbuf = (unsigned short*)(wsf + 6 * ACT + 4718592);  // 16 floats
  float* scores = wsf + 6 * ACT + 4718608;
  float* regs = scores + 76736;
  float* cand_s = regs + 306912;
  float* cand_b = cand_s + 76736;
  int* cand_n = (int*)(cand_b + 306944);
  int* meta = cand_n + 76736;
  float* wt2o = (float*)(meta + 1032);

  // ---- all static weight prep upfront ----
  FcvArgs fa;
  for (int ll = 0; ll < 5; ll++) fa.f[ll] = feats[ll];
  fa.hi = slotB;
  fa.lo = slotB + PLH;
  fa.zbuf = zbuf;
  featcvt_k<<<dim3(135, 8), dim3(256), 0, stream>>>(fa);
  wtro_k<<<dim3(9), dim3(256), 0, stream>>>(cls_ow, reg_ow, wt2o);
  wsplit_k<<<dim3(2304, 4), dim3(256), 0, stream>>>(reg_w, wpkh4, wpkl4);
  WtrArgs wa;
  wa.src = cls_w;
  wa.dst = wt4;
  wtr_k<<<dim3(32, 4, 4), dim3(256), 0, stream>>>(wa);

  float* clsBufs[2] = {clsA, clsB};
  for (int layer = 0; layer < 4; layer++) {
    FusedArgs fu;
    if (layer == 0) {
      fu.in_hi = slotB;
      fu.in_lo = slotB + PLH;
    } else {
      f16* s = (layer & 1) ? slotA : slotB;
      fu.in_hi = s;
      fu.in_lo = s + PLH;
    }
    fu.w_hi = wpkh4 + (size_t)layer * 589824;
    fu.w_lo = wpkl4 + (size_t)layer * 589824;
    fu.acc0 = ACC0;
    fu.acc1 = ACC1;
    fu.zbuf = (const f16*)zbuf;
    fu.cw = wt4 + (size_t)layer * 589824;
    fu.cb = cls_b + layer * 256;
    for (int ll = 0; ll < 5; ll++) {
      fu.cout[ll] = clsBufs[layer & 1] + AOFF[ll];
      fu.cin[ll] = (layer == 0) ? feats[ll]
                                : (const float*)(clsBufs[(layer - 1) & 1] + AOFF[ll]);
    }
    fused_trunk<<<dim3(888), dim3(256), 0, stream>>>(fu);

    EpiArgs ea;
    f16* outS = (layer & 1) ? slotB : slotA;  // L0->A, L1->B, L2->A, L3 in-place fp32
    ea.a0 = ACC0;
    ea.a1 = ACC1;
    ea.bias = reg_b + layer * 256;
    ea.hi = outS;
    ea.lo = outS + PLH;
    ea.last = (layer == 3) ? 1 : 0;
    epi_k<<<dim3(135, 8), dim3(256), 0, stream>>>(ea);
  }

  Out2Args oa;
  for (int ll = 0; ll < 5; ll++) {
    oa.in[0][ll] = clsB + AOFF[ll];
    oa.in[1][ll] = ACC0 + AOFF[ll];
  }
  oa.w = wt2o;
  oa.b[0] = cls_ob;
  oa.b[1] = reg_ob;
  oa.dst[0] = scores;
  oa.dst[1] = regs;
  conv_out2<<<dim3(139, 5), dim3(192), 0, stream>>>(oa);

  init_k<<<dim3(5), dim3(256), 0, stream>>>(meta);
  decode_k<<<dim3((N_ANCH + 255) / 256), dim3(256), 0, stream>>>(scores, regs, cand_s,
                                                                 (float4*)cand_b, cand_n, meta);
  nms2_k<<<dim3(1), dim3(1024), 0, stream>>>(cand_s, (const float4*)cand_b, cand_n, meta,
                                             (float*)d_out);
}